// Round 1
// baseline (1435.833 us; speedup 1.0000x reference)
//
#include <hip/hip_runtime.h>
#include <math.h>

#define DEVFN static __device__ __forceinline__

static constexpr int BB = 8, VV = 13, HH = 32, WW = 64;
static constexpr int NPLANE = HH * WW;        // 2048
static constexpr int NF = BB * VV * NPLANE;   // 212992
static constexpr int NHB = BB * 65 * NPLANE;  // 1064960
static constexpr int NCOL = BB * NPLANE;      // 16384

static constexpr float DT = 300.0f;
static constexpr float KHc = 15.0f, KVc = 0.1f;
static constexpr float OMEGAc = 7.29e-5f;
static constexpr float L_Vc = 2.5e6f;
static constexpr float R_GASc = 8.314f;
static constexpr float C_Pc = 1005.0f;
static constexpr float PTHc = 0.8f;
static constexpr float PYc  = (float)(3.14159265358979323846 * 6371000.0 / 33.0);
static constexpr float PXCc = (float)(2.0 * 3.14159265358979323846 * 6371000.0 / 64.0);
static constexpr float RCCc = (float)(0.7 * 5.67e-8 * 287.0 / (1005.0 * 100.0)); // EMIS*SIGMA*R_D/(C_P*100)
static constexpr float FBIG = 3.402823466e38f;

__constant__ float cDZ[13]  = {50,50,50,50,50,75,100,100,100,125,112,75,75};
__constant__ float cPRS[13] = {50,100,150,200,250,300,400,500,600,700,850,925,1000};

DEVFN int pmh(int r){ return r < 0 ? r + 2 : (r > HH - 1 ? r - 2 : r); }
DEVFN int pmv(int r){ return r < 0 ? r + 2 : (r > VV - 1 ? r - 2 : r); }
DEVFN float latOf(int h){ return (90.0f - (float)(h + 1) * (180.0f / 33.0f)) * 0.017453292519943295f; }
DEVFN float avoid_inf(float t){
  if (t == 0.0f) t = 0.1f;
  if (fabsf(t) < 1.0f) t = copysignf(1.0f, t);
  return t;
}

// ---- stencils on a field laid out [B][13][32][64] ----
// rb = (b*13+v)*2048 + h*64 ; bvbase = (b*13+v)*2048 ; bbase = b*13*2048 ; hw = h*64+w
DEVFN float d_xf(const float* __restrict__ F, int rb, int w, float invpx){
  return (F[rb + ((w + 62) & 63)] - 8.f * F[rb + ((w + 63) & 63)]
        + 8.f * F[rb + ((w + 1) & 63)] - F[rb + ((w + 2) & 63)]) * (1.f / 12.f) * invpx;
}
DEVFN float d_yf(const float* __restrict__ F, int bvbase, int h, int w){
  return (-F[bvbase + pmh(h - 2) * 64 + w] + 8.f * F[bvbase + pmh(h - 1) * 64 + w]
          - 8.f * F[bvbase + pmh(h + 1) * 64 + w] + F[bvbase + pmh(h + 2) * 64 + w]) * (1.f / 12.f) * (1.f / PYc);
}
DEVFN float d_zf(const float* __restrict__ F, int bbase, int v, int hw){
  return (-F[bbase + pmv(v - 2) * 2048 + hw] + 8.f * F[bbase + pmv(v - 1) * 2048 + hw]
          - 8.f * F[bbase + pmv(v + 1) * 2048 + hw] + F[bbase + pmv(v + 2) * 2048 + hw]) * (1.f / 12.f) / cDZ[v];
}
DEVFN float dxxf(const float* __restrict__ F, int rb, int w, float invpx){
  float s = F[rb + ((w + 60) & 63)] - 16.f * F[rb + ((w + 61) & 63)] + 64.f * F[rb + ((w + 62) & 63)]
          + 16.f * F[rb + ((w + 63) & 63)] - 130.f * F[rb + w] + 16.f * F[rb + ((w + 1) & 63)]
          + 64.f * F[rb + ((w + 2) & 63)] - 16.f * F[rb + ((w + 3) & 63)] + F[rb + ((w + 4) & 63)];
  return s * (1.f / 144.f) * invpx * invpx;
}
DEVFN float dyyf(const float* __restrict__ F, int bvbase, int h, int w){
  float g0 = d_yf(F, bvbase, pmh(h - 2), w);
  float g1 = d_yf(F, bvbase, pmh(h - 1), w);
  float g2 = d_yf(F, bvbase, pmh(h + 1), w);
  float g3 = d_yf(F, bvbase, pmh(h + 2), w);
  return (-g0 + 8.f * g1 - 8.f * g2 + g3) * (1.f / 12.f) * (1.f / PYc);
}
DEVFN float dzzf(const float* __restrict__ F, int bbase, int v, int hw){
  float g0 = d_zf(F, bbase, pmv(v - 2), hw);
  float g1 = d_zf(F, bbase, pmv(v - 1), hw);
  float g2 = d_zf(F, bbase, pmv(v + 1), hw);
  float g3 = d_zf(F, bbase, pmv(v + 2), hw);
  return (-g0 + 8.f * g1 - 8.f * g2 + g3) * (1.f / 12.f) / cDZ[v];
}

// ---- reductions ----
DEVFN float waveRedSum(float v){ for (int o = 32; o; o >>= 1) v += __shfl_down(v, o, 64); return v; }
DEVFN float waveRedMin(float v){ for (int o = 32; o; o >>= 1) v = fminf(v, __shfl_down(v, o, 64)); return v; }
DEVFN float waveRedMax(float v){ for (int o = 32; o; o >>= 1) v = fmaxf(v, __shfl_down(v, o, 64)); return v; }

template<int OP>
static __device__ float blockRed(float v){ // 256 threads; all threads get result
  __shared__ float s[4];
  v = OP == 0 ? waveRedSum(v) : OP == 1 ? waveRedMin(v) : waveRedMax(v);
  int lane = threadIdx.x & 63, wid = threadIdx.x >> 6;
  __syncthreads();
  if (lane == 0) s[wid] = v;
  __syncthreads();
  float r;
  if (OP == 0) r = s[0] + s[1] + s[2] + s[3];
  else if (OP == 1) r = fminf(fminf(s[0], s[1]), fminf(s[2], s[3]));
  else r = fmaxf(fmaxf(s[0], s[1]), fmaxf(s[2], s[3]));
  return r;
}

// ---- conv3x3 (zero pad 1), in [B][CIN][32][64], w [COUT][CIN][3][3] ----
template<int CIN>
__global__ void __launch_bounds__(256) conv3x3_k(const float* __restrict__ in,
    const float* __restrict__ wgt, const float* __restrict__ bias,
    float* __restrict__ out, int COUT)
{
  __shared__ __align__(16) float tile[34 * 72];
  int tid = threadIdx.x;
  int co = blockIdx.x, b = blockIdx.y;
  for (int i = tid; i < 34 * 72; i += 256) tile[i] = 0.0f;
  int h = tid >> 3, w0 = (tid & 7) << 3;
  float acc[8] = {0, 0, 0, 0, 0, 0, 0, 0};
  const float* inb = in + (size_t)(b * CIN) * NPLANE;
  const float* wco = wgt + (size_t)co * CIN * 9;
  for (int ci = 0; ci < CIN; ++ci){
    const float4* src = (const float4*)(inb + ci * NPLANE);
    float4 v0 = src[tid], v1 = src[tid + 256];
    __syncthreads();
    {
      int e0 = tid * 4;
      *(float4*)&tile[((e0 >> 6) + 1) * 72 + (e0 & 63) + 4] = v0;
      int e1 = (tid + 256) * 4;
      *(float4*)&tile[((e1 >> 6) + 1) * 72 + (e1 & 63) + 4] = v1;
    }
    __syncthreads();
    const float* wp = wco + ci * 9;
    float wk[9];
    #pragma unroll
    for (int k = 0; k < 9; ++k) wk[k] = wp[k];
    #pragma unroll
    for (int r = 0; r < 3; ++r){
      const float* rowp = &tile[(h + r) * 72 + w0 + 3];
      float xr[10];
      #pragma unroll
      for (int j = 0; j < 10; ++j) xr[j] = rowp[j];
      #pragma unroll
      for (int j = 0; j < 8; ++j)
        acc[j] += xr[j] * wk[r * 3] + xr[j + 1] * wk[r * 3 + 1] + xr[j + 2] * wk[r * 3 + 2];
    }
  }
  float bo = bias[co];
  float* op = out + (size_t)(b * COUT + co) * NPLANE + h * 64 + w0;
  #pragma unroll
  for (int j = 0; j < 8; ++j) op[j] = acc[j] + bo;
}

struct GB { const float* g[5]; const float* b[5]; };

__global__ void __launch_bounds__(256) bn_stats1_k(const float* __restrict__ x, GB gb,
    float* __restrict__ A, float* __restrict__ Bv)
{
  int c = blockIdx.x; // 0..64
  float s = 0.f, s2 = 0.f;
  for (int j = threadIdx.x; j < 16384; j += 256){
    int b = j >> 11, p = j & 2047;
    float v = x[(size_t)(b * 65 + c) * NPLANE + p];
    s += v; s2 += v * v;
  }
  s = blockRed<0>(s);
  s2 = blockRed<0>(s2);
  if (threadIdx.x == 0){
    float m = s * (1.0f / 16384.0f);
    float var = s2 * (1.0f / 16384.0f) - m * m;
    float rstd = rsqrtf(var + 1e-5f);
    int f = c / 13, k = c - f * 13;
    float g = gb.g[f][k], bb = gb.b[f][k];
    A[c] = g * rstd; Bv[c] = bb - m * g * rstd;
  }
}

__global__ void __launch_bounds__(64) prep_k(const float* __restrict__ hb,
  const float* __restrict__ A, const float* __restrict__ Bv,
  float* __restrict__ Fz, float* __restrict__ Fq, float* __restrict__ Fu,
  float* __restrict__ Fvf, float* __restrict__ Ft,
  float* __restrict__ zx, float* __restrict__ zy, float* __restrict__ zz,
  float* __restrict__ ux, float* __restrict__ vy, float* __restrict__ wv,
  float* __restrict__ part)
{
  int col = blockIdx.x * 64 + threadIdx.x; // 0..16383
  int b = col >> 11, p = col & 2047, h = p >> 6, w = p & 63;
  int hbase = b * 65 * NPLANE;
  auto hn = [&](int ch, int hh, int ww)->float {
    return hb[hbase + ch * NPLANE + hh * 64 + ww] * A[ch] + Bv[ch];
  };
  float zc[13], qc[13], uc[13], vc[13], tc[13];
  #pragma unroll
  for (int v = 0; v < 13; ++v){
    zc[v] = hn(v, h, w); qc[v] = hn(13 + v, h, w); uc[v] = hn(26 + v, h, w);
    vc[v] = hn(39 + v, h, w); tc[v] = hn(52 + v, h, w);
  }
  int fb = (b * 13) * 2048 + p;
  #pragma unroll
  for (int v = 0; v < 13; ++v){
    int fi = fb + v * 2048;
    Fz[fi] = zc[v]; Fq[fi] = qc[v]; Fu[fi] = uc[v]; Fvf[fi] = vc[v]; Ft[fi] = tc[v];
    zz[fi] = (-zc[pmv(v - 2)] + 8.f * zc[pmv(v - 1)] - 8.f * zc[pmv(v + 1)] + zc[pmv(v + 2)]) * (1.f / 12.f) / cDZ[v];
  }
  float lat = latOf(h);
  float invpx = 1.0f / (PXCc * cosf(lat));
  int wm2 = (w + 62) & 63, wm1 = (w + 63) & 63, wp1 = (w + 1) & 63, wp2 = (w + 2) & 63;
  int hm2 = pmh(h - 2), hm1 = pmh(h - 1), hp1 = pmh(h + 1), hp2 = pmh(h + 2);
  float cum = 0.f;
  #pragma unroll
  for (int v = 0; v < 13; ++v){
    int fi = fb + v * 2048;
    float zxv = (hn(v, h, wm2) - 8.f * hn(v, h, wm1) + 8.f * hn(v, h, wp1) - hn(v, h, wp2)) * (1.f / 12.f) * invpx;
    float zyv = (-hn(v, hm2, w) + 8.f * hn(v, hm1, w) - 8.f * hn(v, hp1, w) + hn(v, hp2, w)) * (1.f / 12.f) * (1.f / PYc);
    float uxv = (hn(26 + v, h, wm2) - 8.f * hn(26 + v, h, wm1) + 8.f * hn(26 + v, h, wp1) - hn(26 + v, h, wp2)) * (1.f / 12.f) * invpx;
    float vyv = (-hn(39 + v, hm2, w) + 8.f * hn(39 + v, hm1, w) - 8.f * hn(39 + v, hp1, w) + hn(39 + v, hp2, w)) * (1.f / 12.f) * (1.f / PYc);
    zx[fi] = zxv; zy[fi] = zyv; ux[fi] = uxv; vy[fi] = vyv;
    cum += cDZ[v] * (uxv + vyv);
    wv[fi] = -cum;
  }
  // stats: satarg min/max + per-field (min,max,sum)
  float smn = FBIG, smx = -FBIG;
  #pragma unroll
  for (int v = 0; v < 13; ++v){
    float tcc = tc[v] - 273.15f;
    float a = 17.67f * tcc / avoid_inf(tcc + 243.5f);
    smn = fminf(smn, a); smx = fmaxf(smx, a);
  }
  float fmn[5], fmx[5], fsm[5];
  #pragma unroll
  for (int f = 0; f < 5; ++f){
    const float* cc = f == 0 ? zc : f == 1 ? qc : f == 2 ? uc : f == 3 ? vc : tc;
    float mn = cc[0], mx = cc[0], sm = 0.f;
    #pragma unroll
    for (int v = 0; v < 13; ++v){ mn = fminf(mn, cc[v]); mx = fmaxf(mx, cc[v]); sm += cc[v]; }
    fmn[f] = mn; fmx[f] = mx; fsm[f] = sm;
  }
  float r;
  float* pb = part + blockIdx.x * 17;
  r = waveRedMin(smn); if (!threadIdx.x) pb[0] = r;
  r = waveRedMax(smx); if (!threadIdx.x) pb[1] = r;
  #pragma unroll
  for (int f = 0; f < 5; ++f){
    r = waveRedMin(fmn[f]); if (!threadIdx.x) pb[2 + f * 3] = r;
    r = waveRedMax(fmx[f]); if (!threadIdx.x) pb[3 + f * 3] = r;
    r = waveRedSum(fsm[f]); if (!threadIdx.x) pb[4 + f * 3] = r;
  }
}

__global__ void __launch_bounds__(256) finalize1_k(const float* __restrict__ part, float* __restrict__ sc1)
{
  int t = threadIdx.x;
  const float* pr = part + t * 17;
  float smn = blockRed<1>(pr[0]);
  float smx = blockRed<2>(pr[1]);
  float st[15];
  #pragma unroll
  for (int f = 0; f < 5; ++f){
    st[f * 3 + 0] = blockRed<1>(pr[2 + f * 3]);
    st[f * 3 + 1] = blockRed<2>(pr[3 + f * 3]);
    st[f * 3 + 2] = blockRed<0>(pr[4 + f * 3]);
  }
  if (t == 0){
    float ss = (3.01f + 3.47f) / (smx - smn);
    sc1[0] = ss; sc1[1] = -3.47f - smn * ss;
    #pragma unroll
    for (int f = 0; f < 5; ++f){
      sc1[2 + f * 3 + 0] = st[f * 3 + 0];
      sc1[2 + f * 3 + 1] = st[f * 3 + 2] * (1.0f / (float)NF);
      sc1[2 + f * 3 + 2] = st[f * 3 + 1];
    }
  }
}

__global__ void __launch_bounds__(256) qsC0_k(const float* __restrict__ Ft, const float* __restrict__ Fq,
  const float* __restrict__ zz, const float* __restrict__ wv, const float* __restrict__ sc1,
  float* __restrict__ C0, float* __restrict__ prr)
{
  int i = blockIdx.x * 256 + threadIdx.x;
  float t = Ft[i], q = Fq[i], z_z = zz[i], w = wv[i];
  float rho = -1.0f / avoid_inf(z_z);
  float p = rho * R_GASc * t;
  float tcc = t - 273.15f;
  float arg = 17.67f * tcc / avoid_inf(tcc + 243.5f);
  float es = 6.112f * expf(arg * sc1[0] + sc1[1]) * 100.0f;
  float qs = fmaxf(0.622f * es / avoid_inf(p - 0.378f * es), 1e-6f);
  float rh = q / avoid_inf(qs);
  float rate = (rh > PTHc) ? (q - PTHc * qs) * (1.0f / DT) : 0.0f;
  prr[i] = rate;
  C0[i] = -(L_Vc + 1.0f) * z_z * w * (1.0f / C_Pc) + rate * (L_Vc / C_Pc);
}

__global__ void __launch_bounds__(256) uv_stage_k(
  const float* __restrict__ U, const float* __restrict__ Vf,
  const float* __restrict__ u0, const float* __restrict__ v0,
  const float* __restrict__ ux, const float* __restrict__ vy,
  const float* __restrict__ zx, const float* __restrict__ zy,
  const float* __restrict__ wv,
  float* __restrict__ Uo, float* __restrict__ Vo,
  float* __restrict__ duA, float* __restrict__ dvA,
  float* __restrict__ pmm, int stage, float cnext)
{
  int i = blockIdx.x * 256 + threadIdx.x;
  int w = i & 63, h = (i >> 6) & 31;
  int bv = i >> 11;
  int v = bv % 13;
  int bvbase = bv * 2048;
  int rb = bvbase + h * 64;
  int bbase = (bv - v) * 2048;
  int hw = h * 64 + w;
  float lat = latOf(h);
  float invpx = 1.0f / (PXCc * cosf(lat));
  float fcor = 2.0f * OMEGAc * sinf(lat);
  float Ui = U[i], Vi = Vf[i];
  float dyU = d_yf(U, bvbase, h, w);
  float dzU = d_zf(U, bbase, v, hw);
  float dxV = d_xf(Vf, rb, w, invpx);
  float dzV = d_zf(Vf, bbase, v, hw);
  float mixU = KHc * (dxxf(U, rb, w, invpx) + dyyf(U, bvbase, h, w)) + KVc * dzzf(U, bbase, v, hw);
  float mixV = KHc * (dxxf(Vf, rb, w, invpx) + dyyf(Vf, bvbase, h, w)) + KVc * dzzf(Vf, bbase, v, hw);
  float wvi = wv[i];
  float ku = -Ui * ux[i] - Vi * dyU - wvi * dzU + fcor * Vi - zx[i] + mixU;
  float kv = -Ui * dxV - Vi * vy[i] - wvi * dzV - fcor * Ui - zy[i] + mixV;
  if (stage == 1){ duA[i] = ku; dvA[i] = kv; }
  else if (stage < 4){ duA[i] += 2.f * ku; dvA[i] += 2.f * kv; }
  else {
    float au = duA[i] + ku, av = dvA[i] + kv;
    duA[i] = au; dvA[i] = av;
    float m0 = blockRed<1>(au), m1 = blockRed<2>(au);
    float m2 = blockRed<1>(av), m3 = blockRed<2>(av);
    if (!threadIdx.x){ float* pp = pmm + blockIdx.x * 4; pp[0] = m0; pp[1] = m1; pp[2] = m2; pp[3] = m3; }
  }
  if (stage < 4){ Uo[i] = u0[i] + cnext * ku; Vo[i] = v0[i] + cnext * kv; }
}

__global__ void __launch_bounds__(256) t_stage_k(
  const float* __restrict__ T, const float* __restrict__ t0,
  const float* __restrict__ Fu, const float* __restrict__ Fvf,
  const float* __restrict__ wv, const float* __restrict__ C0,
  float* __restrict__ To, float* __restrict__ dtA, float* __restrict__ k4t,
  float* __restrict__ pmm, int stage, float cnext)
{
  int i = blockIdx.x * 256 + threadIdx.x;
  int w = i & 63, h = (i >> 6) & 31;
  int bv = i >> 11;
  int v = bv % 13;
  int bvbase = bv * 2048;
  int rb = bvbase + h * 64;
  int bbase = (bv - v) * 2048;
  int hw = h * 64 + w;
  float lat = latOf(h);
  float invpx = 1.0f / (PXCc * cosf(lat));
  float Ti = T[i];
  float dxT = d_xf(T, rb, w, invpx);
  float dyT = d_yf(T, bvbase, h, w);
  float dzT = d_zf(T, bbase, v, hw);
  float mixT = KHc * (dxxf(T, rb, w, invpx) + dyyf(T, bvbase, h, w)) + KVc * dzzf(T, bbase, v, hw);
  float ta = Ti + 273.15f;
  float t2 = ta * ta;
  float ta5 = t2 * t2 * ta;
  float rc = -RCCc * ta5 / cPRS[v];
  float kt = C0[i] - Fu[i] * dxT - Fvf[i] * dyT - wv[i] * dzT + mixT + rc;
  if (stage == 1) dtA[i] = kt;
  else if (stage < 4) dtA[i] += 2.f * kt;
  else {
    float a = dtA[i] + kt; dtA[i] = a; k4t[i] = kt;
    float m0 = blockRed<1>(a), m1 = blockRed<2>(a);
    if (!threadIdx.x){ pmm[blockIdx.x * 2] = m0; pmm[blockIdx.x * 2 + 1] = m1; }
  }
  if (stage < 4) To[i] = t0[i] + cnext * kt;
}

__global__ void __launch_bounds__(64) zt_k(const float* __restrict__ k4t, float* __restrict__ zt, float* __restrict__ pmm)
{
  int col = blockIdx.x * 64 + threadIdx.x;
  int b = col >> 11, p = col & 2047;
  int fb = b * 13 * 2048 + p;
  float cum = 0.f, mn = FBIG, mx = -FBIG;
  #pragma unroll
  for (int v = 0; v < 13; ++v){
    cum += cDZ[v] * (-R_GASc / cPRS[v]) * k4t[fb + v * 2048];
    zt[fb + v * 2048] = cum;
    mn = fminf(mn, cum); mx = fmaxf(mx, cum);
  }
  mn = waveRedMin(mn); mx = waveRedMax(mx);
  if (!threadIdx.x){ pmm[blockIdx.x * 2] = mn; pmm[blockIdx.x * 2 + 1] = mx; }
}

__global__ void __launch_bounds__(256) qt_k(const float* __restrict__ Fq,
  const float* __restrict__ Fu, const float* __restrict__ Fvf,
  const float* __restrict__ wv, const float* __restrict__ prr,
  float* __restrict__ qt, float* __restrict__ pmm)
{
  int i = blockIdx.x * 256 + threadIdx.x;
  int w = i & 63, h = (i >> 6) & 31;
  int bv = i >> 11;
  int v = bv % 13;
  int bvbase = bv * 2048;
  int rb = bvbase + h * 64;
  int bbase = (bv - v) * 2048;
  int hw = h * 64 + w;
  float lat = latOf(h);
  float invpx = 1.0f / (PXCc * cosf(lat));
  float qtv = -Fu[i] * d_xf(Fq, rb, w, invpx) - Fvf[i] * d_yf(Fq, bvbase, h, w) - wv[i] * d_zf(Fq, bbase, v, hw)
            + KHc * (dxxf(Fq, rb, w, invpx) + dyyf(Fq, bvbase, h, w)) + KVc * dzzf(Fq, bbase, v, hw) - prr[i];
  qt[i] = qtv;
  float m0 = blockRed<1>(qtv), m1 = blockRed<2>(qtv);
  if (!threadIdx.x){ pmm[blockIdx.x * 2] = m0; pmm[blockIdx.x * 2 + 1] = m1; }
}

__global__ void __launch_bounds__(256) finalize2_k(const float* __restrict__ pduv,
  const float* __restrict__ pdt, const float* __restrict__ pqt, const float* __restrict__ pzt,
  const float* __restrict__ sc1, float* __restrict__ sc2)
{
  int t = threadIdx.x;
  float dumn = FBIG, dumx = -FBIG, dvmn = FBIG, dvmx = -FBIG, dtmn = FBIG, dtmx = -FBIG;
  float qmn = FBIG, qmx = -FBIG, zmn = FBIG, zmx = -FBIG;
  for (int j = t; j < 832; j += 256){
    dumn = fminf(dumn, pduv[j * 4]);     dumx = fmaxf(dumx, pduv[j * 4 + 1]);
    dvmn = fminf(dvmn, pduv[j * 4 + 2]); dvmx = fmaxf(dvmx, pduv[j * 4 + 3]);
    dtmn = fminf(dtmn, pdt[j * 2]);      dtmx = fmaxf(dtmx, pdt[j * 2 + 1]);
    qmn = fminf(qmn, pqt[j * 2]);        qmx = fmaxf(qmx, pqt[j * 2 + 1]);
  }
  if (t < 256){ zmn = fminf(zmn, pzt[t * 2]); zmx = fmaxf(zmx, pzt[t * 2 + 1]); }
  dumn = blockRed<1>(dumn); dumx = blockRed<2>(dumx);
  dvmn = blockRed<1>(dvmn); dvmx = blockRed<2>(dvmx);
  dtmn = blockRed<1>(dtmn); dtmx = blockRed<2>(dtmx);
  qmn = blockRed<1>(qmn);   qmx = blockRed<2>(qmx);
  zmn = blockRed<1>(zmn);   zmx = blockRed<2>(zmx);
  if (t == 0){
    float rmn[5] = {zmn, qmn, dumn, dvmn, dtmn};
    float rmx[5] = {zmx, qmx, dumx, dvmx, dtmx};
    float cfs[5] = {DT, DT, DT / 6.f, DT / 6.f, DT / 6.f};
    #pragma unroll
    for (int f = 0; f < 5; ++f){
      float mnf = sc1[2 + f * 3], mef = sc1[3 + f * 3], mxf = sc1[4 + f * 3];
      float a = (mnf - mef) * 0.05f, b2 = (mxf - mef) * 0.05f;
      float cf = cfs[f];
      float dmn = rmn[f] * cf, dmx = rmx[f] * cf;
      float s = (b2 - a) / (dmx - dmn);
      sc2[f * 2] = s * cf;
      sc2[f * 2 + 1] = a - dmn * s;
    }
  }
}

__global__ void __launch_bounds__(256) outmid_k(const float* __restrict__ hb,
  const float* __restrict__ Fz, const float* __restrict__ Fq, const float* __restrict__ Fu,
  const float* __restrict__ Fvf, const float* __restrict__ Ft,
  const float* __restrict__ zt, const float* __restrict__ qt,
  const float* __restrict__ duA, const float* __restrict__ dvA, const float* __restrict__ dtA,
  const float* __restrict__ coef, const float* __restrict__ sc2, float* __restrict__ mid)
{
  int e = blockIdx.x * 256 + threadIdx.x;
  int b = e / (65 * 2048);
  int r = e - b * 65 * 2048;
  int c = r >> 11, p = r & 2047;
  int f = c / 13, v = c - f * 13;
  int fi = (b * 13 + v) * 2048 + p;
  const float* Fp; const float* Rp;
  switch (f){
    case 0: Fp = Fz; Rp = zt; break;
    case 1: Fp = Fq; Rp = qt; break;
    case 2: Fp = Fu; Rp = duA; break;
    case 3: Fp = Fvf; Rp = dvA; break;
    default: Fp = Ft; Rp = dtA; break;
  }
  float phys = Fp[fi] + Rp[fi] * sc2[f * 2] + sc2[f * 2 + 1];
  float cf = coef[c * 2048 + p];
  mid[e] = cf * phys + (1.0f - cf) * hb[e];
}

__global__ void __launch_bounds__(256) bn_stats2_k(const float* __restrict__ y,
  const float* __restrict__ g, const float* __restrict__ bb, float* __restrict__ A, float* __restrict__ Bv)
{
  int c = blockIdx.x;
  float s = 0.f, s2 = 0.f;
  for (int j = threadIdx.x; j < 16384; j += 256){
    int b = j >> 11, p = j & 2047;
    float v = y[(size_t)(b * 256 + c) * 2048 + p];
    s += v; s2 += v * v;
  }
  s = blockRed<0>(s);
  s2 = blockRed<0>(s2);
  if (!threadIdx.x){
    float m = s * (1.0f / 16384.0f);
    float var = s2 * (1.0f / 16384.0f) - m * m;
    float rstd = rsqrtf(var + 1e-5f);
    A[c] = g[c] * rstd; Bv[c] = bb[c] - m * g[c] * rstd;
  }
}

__global__ void __launch_bounds__(256) final_k(float* __restrict__ y, const float* __restrict__ x,
  const float* __restrict__ A, const float* __restrict__ Bv)
{
  int e4 = blockIdx.x * 256 + threadIdx.x;
  int c = (e4 >> 9) & 255;
  float4 v = ((const float4*)y)[e4];
  float4 xv = ((const float4*)x)[e4];
  float a = A[c], bb = Bv[c];
  v.x = v.x * a + bb + xv.x;
  v.y = v.y * a + bb + xv.y;
  v.z = v.z * a + bb + xv.z;
  v.w = v.w * a + bb + xv.w;
  ((float4*)y)[e4] = v;
}

extern "C" void kernel_launch(void* const* d_in, const int* in_sizes, int n_in,
                              void* d_out, int out_size, void* d_ws, size_t ws_size,
                              hipStream_t stream)
{
  (void)in_sizes; (void)n_in; (void)out_size; (void)ws_size;
  const float* x        = (const float*)d_in[0];
  const float* w_norm   = (const float*)d_in[1];
  const float* b_norm   = (const float*)d_in[2];
  const float* w_innorm = (const float*)d_in[3];
  const float* b_innorm = (const float*)d_in[4];
  const float* coef     = (const float*)d_in[5];
  GB gb;
  for (int f = 0; f < 5; ++f){
    gb.g[f] = (const float*)d_in[6 + 2 * f];
    gb.b[f] = (const float*)d_in[7 + 2 * f];
  }
  const float* gblk = (const float*)d_in[16];
  const float* bblk = (const float*)d_in[17];
  float* yout = (float*)d_out;

  float* ws = (float*)d_ws;
  size_t off = 0;
  auto alloc = [&](size_t n){ float* p = ws + off; off += n; return p; };
  float* hb  = alloc(NHB);
  float* Fz  = alloc(NF); float* Fq  = alloc(NF); float* Fu  = alloc(NF);
  float* Fvf = alloc(NF); float* Ft  = alloc(NF);
  float* zx  = alloc(NF); float* zy  = alloc(NF); float* zz  = alloc(NF);
  float* ux  = alloc(NF); float* vy  = alloc(NF); float* wvel = alloc(NF);
  float* C0  = alloc(NF); float* prr = alloc(NF);
  float* Ua  = alloc(NF); float* Ub  = alloc(NF); float* Va  = alloc(NF); float* Vb = alloc(NF);
  float* Ta  = alloc(NF); float* Tb  = alloc(NF);
  float* duA = alloc(NF); float* dvA = alloc(NF); float* dtA = alloc(NF);
  float* k4t = alloc(NF); float* ztA = alloc(NF); float* qtA = alloc(NF);
  float* A1 = alloc(65);  float* B1 = alloc(65);
  float* A2 = alloc(256); float* B2 = alloc(256);
  float* sc1 = alloc(32); float* sc2 = alloc(16);
  float* part1 = alloc(256 * 17);
  float* pduv = alloc(832 * 4); float* pdt = alloc(832 * 2);
  float* pqt  = alloc(832 * 2); float* pzt = alloc(256 * 2);
  // mid aliases Ua..Ta region (1064960 floats): all stage buffers are dead by the time
  // outmid_k runs (last reads: uv stage4 reads Ua/Va, t stage4 reads Ta).
  float* mid = Ua;

  dim3 g1(65, 8);
  conv3x3_k<256><<<g1, 256, 0, stream>>>(x, w_norm, b_norm, hb, 65);
  bn_stats1_k<<<65, 256, 0, stream>>>(hb, gb, A1, B1);
  prep_k<<<NCOL / 64, 64, 0, stream>>>(hb, A1, B1, Fz, Fq, Fu, Fvf, Ft, zx, zy, zz, ux, vy, wvel, part1);
  finalize1_k<<<1, 256, 0, stream>>>(part1, sc1);
  qsC0_k<<<NF / 256, 256, 0, stream>>>(Ft, Fq, zz, wvel, sc1, C0, prr);
  // RK4 u/v
  uv_stage_k<<<NF / 256, 256, 0, stream>>>(Fu, Fvf, Fu, Fvf, ux, vy, zx, zy, wvel, Ua, Va, duA, dvA, pduv, 1, 0.5f * DT);
  uv_stage_k<<<NF / 256, 256, 0, stream>>>(Ua, Va, Fu, Fvf, ux, vy, zx, zy, wvel, Ub, Vb, duA, dvA, pduv, 2, 0.5f * DT);
  uv_stage_k<<<NF / 256, 256, 0, stream>>>(Ub, Vb, Fu, Fvf, ux, vy, zx, zy, wvel, Ua, Va, duA, dvA, pduv, 3, DT);
  uv_stage_k<<<NF / 256, 256, 0, stream>>>(Ua, Va, Fu, Fvf, ux, vy, zx, zy, wvel, Ub, Vb, duA, dvA, pduv, 4, 0.f);
  // RK4 t
  t_stage_k<<<NF / 256, 256, 0, stream>>>(Ft, Ft, Fu, Fvf, wvel, C0, Ta, dtA, k4t, pdt, 1, 0.5f * DT);
  t_stage_k<<<NF / 256, 256, 0, stream>>>(Ta, Ft, Fu, Fvf, wvel, C0, Tb, dtA, k4t, pdt, 2, 0.5f * DT);
  t_stage_k<<<NF / 256, 256, 0, stream>>>(Tb, Ft, Fu, Fvf, wvel, C0, Ta, dtA, k4t, pdt, 3, DT);
  t_stage_k<<<NF / 256, 256, 0, stream>>>(Ta, Ft, Fu, Fvf, wvel, C0, Tb, dtA, k4t, pdt, 4, 0.f);
  zt_k<<<NCOL / 64, 64, 0, stream>>>(k4t, ztA, pzt);
  qt_k<<<NF / 256, 256, 0, stream>>>(Fq, Fu, Fvf, wvel, prr, qtA, pqt);
  finalize2_k<<<1, 256, 0, stream>>>(pduv, pdt, pqt, pzt, sc1, sc2);
  outmid_k<<<NHB / 256, 256, 0, stream>>>(hb, Fz, Fq, Fu, Fvf, Ft, ztA, qtA, duA, dvA, dtA, coef, sc2, mid);
  dim3 g2(256, 8);
  conv3x3_k<65><<<g2, 256, 0, stream>>>(mid, w_innorm, b_innorm, yout, 256);
  bn_stats2_k<<<256, 256, 0, stream>>>(yout, gblk, bblk, A2, B2);
  final_k<<<(NHB * 0 + 4194304 / 4) / 256, 256, 0, stream>>>(yout, x, A2, B2);
}

// Round 2
// 231.852 us; speedup vs baseline: 6.1929x; 6.1929x over previous
//
#include <hip/hip_runtime.h>
#include <math.h>

#define DEVFN static __device__ __forceinline__

static constexpr int BB = 8, VV = 13, HH = 32, WW = 64;
static constexpr int NPLANE = HH * WW;        // 2048
static constexpr int NF = BB * VV * NPLANE;   // 212992
static constexpr int NHB = BB * 65 * NPLANE;  // 1064960
static constexpr int NCOL = BB * NPLANE;      // 16384

static constexpr float DT = 300.0f;
static constexpr float KHc = 15.0f, KVc = 0.1f;
static constexpr float OMEGAc = 7.29e-5f;
static constexpr float L_Vc = 2.5e6f;
static constexpr float R_GASc = 8.314f;
static constexpr float C_Pc = 1005.0f;
static constexpr float PTHc = 0.8f;
static constexpr float PYc  = (float)(3.14159265358979323846 * 6371000.0 / 33.0);
static constexpr float PXCc = (float)(2.0 * 3.14159265358979323846 * 6371000.0 / 64.0);
static constexpr float RCCc = (float)(0.7 * 5.67e-8 * 287.0 / (1005.0 * 100.0));
static constexpr float FBIG = 3.402823466e38f;

__constant__ float cDZ[13]  = {50,50,50,50,50,75,100,100,100,125,112,75,75};
__constant__ float cPRS[13] = {50,100,150,200,250,300,400,500,600,700,850,925,1000};

typedef short bf16x8 __attribute__((ext_vector_type(8)));
typedef float f32x4 __attribute__((ext_vector_type(4)));

DEVFN int pmh(int r){ return r < 0 ? r + 2 : (r > HH - 1 ? r - 2 : r); }
DEVFN int pmv(int r){ return r < 0 ? r + 2 : (r > VV - 1 ? r - 2 : r); }
DEVFN float latOf(int h){ return (90.0f - (float)(h + 1) * (180.0f / 33.0f)) * 0.017453292519943295f; }
DEVFN float avoid_inf(float t){
  if (t == 0.0f) t = 0.1f;
  if (fabsf(t) < 1.0f) t = copysignf(1.0f, t);
  return t;
}
DEVFN unsigned short f2bf(float f){
  unsigned u = __float_as_uint(f);
  unsigned r = (u + 0x7fffu + ((u >> 16) & 1u)) >> 16;
  return (unsigned short)r;
}

// ---- stencils on a field laid out [B][13][32][64] ----
DEVFN float d_xf(const float* __restrict__ F, int rb, int w, float invpx){
  return (F[rb + ((w + 62) & 63)] - 8.f * F[rb + ((w + 63) & 63)]
        + 8.f * F[rb + ((w + 1) & 63)] - F[rb + ((w + 2) & 63)]) * (1.f / 12.f) * invpx;
}
DEVFN float d_yf(const float* __restrict__ F, int bvbase, int h, int w){
  return (-F[bvbase + pmh(h - 2) * 64 + w] + 8.f * F[bvbase + pmh(h - 1) * 64 + w]
          - 8.f * F[bvbase + pmh(h + 1) * 64 + w] + F[bvbase + pmh(h + 2) * 64 + w]) * (1.f / 12.f) * (1.f / PYc);
}
DEVFN float d_zf(const float* __restrict__ F, int bbase, int v, int hw){
  return (-F[bbase + pmv(v - 2) * 2048 + hw] + 8.f * F[bbase + pmv(v - 1) * 2048 + hw]
          - 8.f * F[bbase + pmv(v + 1) * 2048 + hw] + F[bbase + pmv(v + 2) * 2048 + hw]) * (1.f / 12.f) / cDZ[v];
}
DEVFN float dxxf(const float* __restrict__ F, int rb, int w, float invpx){
  float s = F[rb + ((w + 60) & 63)] - 16.f * F[rb + ((w + 61) & 63)] + 64.f * F[rb + ((w + 62) & 63)]
          + 16.f * F[rb + ((w + 63) & 63)] - 130.f * F[rb + w] + 16.f * F[rb + ((w + 1) & 63)]
          + 64.f * F[rb + ((w + 2) & 63)] - 16.f * F[rb + ((w + 3) & 63)] + F[rb + ((w + 4) & 63)];
  return s * (1.f / 144.f) * invpx * invpx;
}
DEVFN float dyyf(const float* __restrict__ F, int bvbase, int h, int w){
  float g0 = d_yf(F, bvbase, pmh(h - 2), w);
  float g1 = d_yf(F, bvbase, pmh(h - 1), w);
  float g2 = d_yf(F, bvbase, pmh(h + 1), w);
  float g3 = d_yf(F, bvbase, pmh(h + 2), w);
  return (-g0 + 8.f * g1 - 8.f * g2 + g3) * (1.f / 12.f) * (1.f / PYc);
}
DEVFN float dzzf(const float* __restrict__ F, int bbase, int v, int hw){
  float g0 = d_zf(F, bbase, pmv(v - 2), hw);
  float g1 = d_zf(F, bbase, pmv(v - 1), hw);
  float g2 = d_zf(F, bbase, pmv(v + 1), hw);
  float g3 = d_zf(F, bbase, pmv(v + 2), hw);
  return (-g0 + 8.f * g1 - 8.f * g2 + g3) * (1.f / 12.f) / cDZ[v];
}

// ---- reductions ----
DEVFN float waveRedSum(float v){ for (int o = 32; o; o >>= 1) v += __shfl_down(v, o, 64); return v; }
DEVFN float waveRedMin(float v){ for (int o = 32; o; o >>= 1) v = fminf(v, __shfl_down(v, o, 64)); return v; }
DEVFN float waveRedMax(float v){ for (int o = 32; o; o >>= 1) v = fmaxf(v, __shfl_down(v, o, 64)); return v; }

template<int OP>
static __device__ float blockRed(float v){
  __shared__ float s[4];
  v = OP == 0 ? waveRedSum(v) : OP == 1 ? waveRedMin(v) : waveRedMax(v);
  int lane = threadIdx.x & 63, wid = threadIdx.x >> 6;
  __syncthreads();
  if (lane == 0) s[wid] = v;
  __syncthreads();
  float r;
  if (OP == 0) r = s[0] + s[1] + s[2] + s[3];
  else if (OP == 1) r = fminf(fminf(s[0], s[1]), fminf(s[2], s[3]));
  else r = fmaxf(fmaxf(s[0], s[1]), fmaxf(s[2], s[3]));
  return r;
}

// ================= conv via MFMA =================
// transpose [B][CI][32][64] f32 -> [B][32][64][CIT] bf16 (ci >= CI zero-padded)
template<int CI, int CIT>
__global__ void __launch_bounds__(256) transpose_in_k(const float* __restrict__ x,
    unsigned short* __restrict__ XT)
{
  __shared__ float tile[16 * 68];
  int h = blockIdx.x, b = blockIdx.y;
  int t = threadIdx.x;
  const int NP = CIT / 16;
  for (int p = 0; p < NP; ++p){
    int cbase = p * 16;
    if (p) __syncthreads();
    {
      int cl = t >> 4, w4 = (t & 15) * 4;
      int ci = cbase + cl;
      float4 v = make_float4(0.f, 0.f, 0.f, 0.f);
      if (ci < CI) v = *(const float4*)(x + (((size_t)(b * CI + ci) * 32 + h) * 64 + w4));
      tile[cl * 68 + w4 + 0] = v.x; tile[cl * 68 + w4 + 1] = v.y;
      tile[cl * 68 + w4 + 2] = v.z; tile[cl * 68 + w4 + 3] = v.w;
    }
    __syncthreads();
    {
      int w = t >> 2, c4 = (t & 3) * 4;
      ushort4 o;
      o.x = f2bf(tile[(c4 + 0) * 68 + w]);
      o.y = f2bf(tile[(c4 + 1) * 68 + w]);
      o.z = f2bf(tile[(c4 + 2) * 68 + w]);
      o.w = f2bf(tile[(c4 + 3) * 68 + w]);
      *(ushort4*)(XT + (((size_t)(b * 32 + h) * 64 + w) * CIT + cbase + c4)) = o;
    }
  }
}

// W [CO][CI][3][3] f32 -> Wp [9][COp][CIp] bf16 (pads zero)
__global__ void __launch_bounds__(256) packW_k(const float* __restrict__ w,
    unsigned short* __restrict__ wp, int CO, int CI, int COp, int CIp)
{
  int idx = blockIdx.x * 256 + threadIdx.x;
  int total = 9 * COp * CIp;
  if (idx >= total) return;
  int dir = idx / (COp * CIp);
  int r = idx - dir * (COp * CIp);
  int co = r / CIp, ci = r - co * CIp;
  float v = (co < CO && ci < CI) ? w[((size_t)(co * CI + ci)) * 9 + dir] : 0.f;
  wp[idx] = f2bf(v);
}

// Implicit-GEMM conv3x3 (zero pad). Block = one (b,h) row of 64 pixels.
// CIT: total padded in-channels in XT; CIL: LDS ci-chunk; COp: padded out-ch.
// NW waves, MF m-frags (16 co) per wave. D[m=co][n=pix] = sum_ci Wp*Xl.
template<int CIT, int CIL, int CO, int COp, int NW, int MF, int SWZ>
__global__ void __launch_bounds__(NW * 64) conv_mfma_k(
    const unsigned short* __restrict__ XT, const unsigned short* __restrict__ Wp,
    const float* __restrict__ bias, float* __restrict__ out)
{
  __shared__ __align__(16) unsigned short Xl[3 * 66 * CIL];
  const int C8 = CIL / 8;
  int tid = threadIdx.x;
  int h = blockIdx.x, b = blockIdx.y;
  int wid = tid >> 6, lane = tid & 63;
  int l15 = lane & 15, q = lane >> 4;

  f32x4 acc[MF][4];
  #pragma unroll
  for (int mf = 0; mf < MF; ++mf)
    #pragma unroll
    for (int nf = 0; nf < 4; ++nf){ f32x4 z = {0.f, 0.f, 0.f, 0.f}; acc[mf][nf] = z; }

  for (int cp = 0; cp < CIT / CIL; ++cp){
    if (cp) __syncthreads();
    // stage rows h-1..h+1, w=0..63 into Xl[r][j=w+1][ci], swizzled; halo j=0,65 zero
    for (int idx = tid; idx < 3 * 64 * C8; idx += NW * 64){
      int r = idx / (64 * C8);
      int rest = idx - r * 64 * C8;
      int j1 = rest / C8;
      int c8 = rest - j1 * C8;
      int j = j1 + 1;
      int hh = h + r - 1;
      uint4 val = make_uint4(0, 0, 0, 0);
      if (hh >= 0 && hh < 32)
        val = *(const uint4*)(XT + (((size_t)(b * 32 + hh) * 64 + j1) * CIT + cp * CIL + c8 * 8));
      int dst = (r * 66 + j) * CIL + ((c8 * 8) ^ ((j & SWZ) << 3));
      *(uint4*)(Xl + dst) = val;
    }
    for (int idx = tid; idx < 3 * 2 * C8; idx += NW * 64){
      int r = idx / (2 * C8);
      int rest = idx - r * 2 * C8;
      int js = rest / C8;
      int c8 = rest - js * C8;
      int j = js ? 65 : 0;
      int dst = (r * 66 + j) * CIL + ((c8 * 8) ^ ((j & SWZ) << 3));
      *(uint4*)(Xl + dst) = make_uint4(0, 0, 0, 0);
    }
    __syncthreads();

    for (int dir = 0; dir < 9; ++dir){
      int dy = dir / 3, dx = dir - dy * 3;
      #pragma unroll
      for (int kc = 0; kc < CIL / 32; ++kc){
        int kb = kc * 32 + q * 8;
        bf16x8 a[MF];
        #pragma unroll
        for (int mf = 0; mf < MF; ++mf){
          int co = wid * (MF * 16) + mf * 16 + l15;
          a[mf] = *(const bf16x8*)(Wp + ((size_t)(dir * COp + co) * CIT + cp * CIL + kb));
        }
        #pragma unroll
        for (int nf = 0; nf < 4; ++nf){
          int j = nf * 16 + l15 + dx;
          bf16x8 bfrag = *(const bf16x8*)(Xl + ((dy * 66 + j) * CIL + (kb ^ ((j & SWZ) << 3))));
          #pragma unroll
          for (int mf = 0; mf < MF; ++mf)
            acc[mf][nf] = __builtin_amdgcn_mfma_f32_16x16x32_bf16(a[mf], bfrag, acc[mf][nf], 0, 0, 0);
        }
      }
    }
  }
  // store: D row = co-local = q*4 + r, col = pix = nf*16 + l15
  #pragma unroll
  for (int mf = 0; mf < MF; ++mf){
    #pragma unroll
    for (int r = 0; r < 4; ++r){
      int co = wid * (MF * 16) + mf * 16 + q * 4 + r;
      if (CO != COp && co >= CO) continue;
      float bv = bias[co];
      #pragma unroll
      for (int nf = 0; nf < 4; ++nf){
        int pix = nf * 16 + l15;
        out[(size_t)(b * CO + co) * 2048 + h * 64 + pix] = acc[mf][nf][r] + bv;
      }
    }
  }
}

// ================= rest of pipeline (unchanged from R1) =================
struct GB { const float* g[5]; const float* b[5]; };

__global__ void __launch_bounds__(256) bn_stats1_k(const float* __restrict__ x, GB gb,
    float* __restrict__ A, float* __restrict__ Bv)
{
  int c = blockIdx.x;
  float s = 0.f, s2 = 0.f;
  for (int j = threadIdx.x; j < 16384; j += 256){
    int b = j >> 11, p = j & 2047;
    float v = x[(size_t)(b * 65 + c) * NPLANE + p];
    s += v; s2 += v * v;
  }
  s = blockRed<0>(s);
  s2 = blockRed<0>(s2);
  if (threadIdx.x == 0){
    float m = s * (1.0f / 16384.0f);
    float var = s2 * (1.0f / 16384.0f) - m * m;
    float rstd = rsqrtf(var + 1e-5f);
    int f = c / 13, k = c - f * 13;
    float g = gb.g[f][k], bb = gb.b[f][k];
    A[c] = g * rstd; Bv[c] = bb - m * g * rstd;
  }
}

__global__ void __launch_bounds__(64) prep_k(const float* __restrict__ hb,
  const float* __restrict__ A, const float* __restrict__ Bv,
  float* __restrict__ Fz, float* __restrict__ Fq, float* __restrict__ Fu,
  float* __restrict__ Fvf, float* __restrict__ Ft,
  float* __restrict__ zx, float* __restrict__ zy, float* __restrict__ zz,
  float* __restrict__ ux, float* __restrict__ vy, float* __restrict__ wv,
  float* __restrict__ part)
{
  int col = blockIdx.x * 64 + threadIdx.x;
  int b = col >> 11, p = col & 2047, h = p >> 6, w = p & 63;
  int hbase = b * 65 * NPLANE;
  auto hn = [&](int ch, int hh, int ww)->float {
    return hb[hbase + ch * NPLANE + hh * 64 + ww] * A[ch] + Bv[ch];
  };
  float zc[13], qc[13], uc[13], vc[13], tc[13];
  #pragma unroll
  for (int v = 0; v < 13; ++v){
    zc[v] = hn(v, h, w); qc[v] = hn(13 + v, h, w); uc[v] = hn(26 + v, h, w);
    vc[v] = hn(39 + v, h, w); tc[v] = hn(52 + v, h, w);
  }
  int fb = (b * 13) * 2048 + p;
  #pragma unroll
  for (int v = 0; v < 13; ++v){
    int fi = fb + v * 2048;
    Fz[fi] = zc[v]; Fq[fi] = qc[v]; Fu[fi] = uc[v]; Fvf[fi] = vc[v]; Ft[fi] = tc[v];
    zz[fi] = (-zc[pmv(v - 2)] + 8.f * zc[pmv(v - 1)] - 8.f * zc[pmv(v + 1)] + zc[pmv(v + 2)]) * (1.f / 12.f) / cDZ[v];
  }
  float lat = latOf(h);
  float invpx = 1.0f / (PXCc * cosf(lat));
  int wm2 = (w + 62) & 63, wm1 = (w + 63) & 63, wp1 = (w + 1) & 63, wp2 = (w + 2) & 63;
  int hm2 = pmh(h - 2), hm1 = pmh(h - 1), hp1 = pmh(h + 1), hp2 = pmh(h + 2);
  float cum = 0.f;
  #pragma unroll
  for (int v = 0; v < 13; ++v){
    int fi = fb + v * 2048;
    float zxv = (hn(v, h, wm2) - 8.f * hn(v, h, wm1) + 8.f * hn(v, h, wp1) - hn(v, h, wp2)) * (1.f / 12.f) * invpx;
    float zyv = (-hn(v, hm2, w) + 8.f * hn(v, hm1, w) - 8.f * hn(v, hp1, w) + hn(v, hp2, w)) * (1.f / 12.f) * (1.f / PYc);
    float uxv = (hn(26 + v, h, wm2) - 8.f * hn(26 + v, h, wm1) + 8.f * hn(26 + v, h, wp1) - hn(26 + v, h, wp2)) * (1.f / 12.f) * invpx;
    float vyv = (-hn(39 + v, hm2, w) + 8.f * hn(39 + v, hm1, w) - 8.f * hn(39 + v, hp1, w) + hn(39 + v, hp2, w)) * (1.f / 12.f) * (1.f / PYc);
    zx[fi] = zxv; zy[fi] = zyv; ux[fi] = uxv; vy[fi] = vyv;
    cum += cDZ[v] * (uxv + vyv);
    wv[fi] = -cum;
  }
  float smn = FBIG, smx = -FBIG;
  #pragma unroll
  for (int v = 0; v < 13; ++v){
    float tcc = tc[v] - 273.15f;
    float a = 17.67f * tcc / avoid_inf(tcc + 243.5f);
    smn = fminf(smn, a); smx = fmaxf(smx, a);
  }
  float fmn[5], fmx[5], fsm[5];
  #pragma unroll
  for (int f = 0; f < 5; ++f){
    const float* cc = f == 0 ? zc : f == 1 ? qc : f == 2 ? uc : f == 3 ? vc : tc;
    float mn = cc[0], mx = cc[0], sm = 0.f;
    #pragma unroll
    for (int v = 0; v < 13; ++v){ mn = fminf(mn, cc[v]); mx = fmaxf(mx, cc[v]); sm += cc[v]; }
    fmn[f] = mn; fmx[f] = mx; fsm[f] = sm;
  }
  float r;
  float* pb = part + blockIdx.x * 17;
  r = waveRedMin(smn); if (!threadIdx.x) pb[0] = r;
  r = waveRedMax(smx); if (!threadIdx.x) pb[1] = r;
  #pragma unroll
  for (int f = 0; f < 5; ++f){
    r = waveRedMin(fmn[f]); if (!threadIdx.x) pb[2 + f * 3] = r;
    r = waveRedMax(fmx[f]); if (!threadIdx.x) pb[3 + f * 3] = r;
    r = waveRedSum(fsm[f]); if (!threadIdx.x) pb[4 + f * 3] = r;
  }
}

__global__ void __launch_bounds__(256) finalize1_k(const float* __restrict__ part, float* __restrict__ sc1)
{
  int t = threadIdx.x;
  const float* pr = part + t * 17;
  float smn = blockRed<1>(pr[0]);
  float smx = blockRed<2>(pr[1]);
  float st[15];
  #pragma unroll
  for (int f = 0; f < 5; ++f){
    st[f * 3 + 0] = blockRed<1>(pr[2 + f * 3]);
    st[f * 3 + 1] = blockRed<2>(pr[3 + f * 3]);
    st[f * 3 + 2] = blockRed<0>(pr[4 + f * 3]);
  }
  if (t == 0){
    float ss = (3.01f + 3.47f) / (smx - smn);
    sc1[0] = ss; sc1[1] = -3.47f - smn * ss;
    #pragma unroll
    for (int f = 0; f < 5; ++f){
      sc1[2 + f * 3 + 0] = st[f * 3 + 0];
      sc1[2 + f * 3 + 1] = st[f * 3 + 2] * (1.0f / (float)NF);
      sc1[2 + f * 3 + 2] = st[f * 3 + 1];
    }
  }
}

__global__ void __launch_bounds__(256) qsC0_k(const float* __restrict__ Ft, const float* __restrict__ Fq,
  const float* __restrict__ zz, const float* __restrict__ wv, const float* __restrict__ sc1,
  float* __restrict__ C0, float* __restrict__ prr)
{
  int i = blockIdx.x * 256 + threadIdx.x;
  float t = Ft[i], q = Fq[i], z_z = zz[i], w = wv[i];
  float rho = -1.0f / avoid_inf(z_z);
  float p = rho * R_GASc * t;
  float tcc = t - 273.15f;
  float arg = 17.67f * tcc / avoid_inf(tcc + 243.5f);
  float es = 6.112f * expf(arg * sc1[0] + sc1[1]) * 100.0f;
  float qs = fmaxf(0.622f * es / avoid_inf(p - 0.378f * es), 1e-6f);
  float rh = q / avoid_inf(qs);
  float rate = (rh > PTHc) ? (q - PTHc * qs) * (1.0f / DT) : 0.0f;
  prr[i] = rate;
  C0[i] = -(L_Vc + 1.0f) * z_z * w * (1.0f / C_Pc) + rate * (L_Vc / C_Pc);
}

__global__ void __launch_bounds__(256) uv_stage_k(
  const float* __restrict__ U, const float* __restrict__ Vf,
  const float* __restrict__ u0, const float* __restrict__ v0,
  const float* __restrict__ ux, const float* __restrict__ vy,
  const float* __restrict__ zx, const float* __restrict__ zy,
  const float* __restrict__ wv,
  float* __restrict__ Uo, float* __restrict__ Vo,
  float* __restrict__ duA, float* __restrict__ dvA,
  float* __restrict__ pmm, int stage, float cnext)
{
  int i = blockIdx.x * 256 + threadIdx.x;
  int w = i & 63, h = (i >> 6) & 31;
  int bv = i >> 11;
  int v = bv % 13;
  int bvbase = bv * 2048;
  int rb = bvbase + h * 64;
  int bbase = (bv - v) * 2048;
  int hw = h * 64 + w;
  float lat = latOf(h);
  float invpx = 1.0f / (PXCc * cosf(lat));
  float fcor = 2.0f * OMEGAc * sinf(lat);
  float Ui = U[i], Vi = Vf[i];
  float dyU = d_yf(U, bvbase, h, w);
  float dzU = d_zf(U, bbase, v, hw);
  float dxV = d_xf(Vf, rb, w, invpx);
  float dzV = d_zf(Vf, bbase, v, hw);
  float mixU = KHc * (dxxf(U, rb, w, invpx) + dyyf(U, bvbase, h, w)) + KVc * dzzf(U, bbase, v, hw);
  float mixV = KHc * (dxxf(Vf, rb, w, invpx) + dyyf(Vf, bvbase, h, w)) + KVc * dzzf(Vf, bbase, v, hw);
  float wvi = wv[i];
  float ku = -Ui * ux[i] - Vi * dyU - wvi * dzU + fcor * Vi - zx[i] + mixU;
  float kv = -Ui * dxV - Vi * vy[i] - wvi * dzV - fcor * Ui - zy[i] + mixV;
  if (stage == 1){ duA[i] = ku; dvA[i] = kv; }
  else if (stage < 4){ duA[i] += 2.f * ku; dvA[i] += 2.f * kv; }
  else {
    float au = duA[i] + ku, av = dvA[i] + kv;
    duA[i] = au; dvA[i] = av;
    float m0 = blockRed<1>(au), m1 = blockRed<2>(au);
    float m2 = blockRed<1>(av), m3 = blockRed<2>(av);
    if (!threadIdx.x){ float* pp = pmm + blockIdx.x * 4; pp[0] = m0; pp[1] = m1; pp[2] = m2; pp[3] = m3; }
  }
  if (stage < 4){ Uo[i] = u0[i] + cnext * ku; Vo[i] = v0[i] + cnext * kv; }
}

__global__ void __launch_bounds__(256) t_stage_k(
  const float* __restrict__ T, const float* __restrict__ t0,
  const float* __restrict__ Fu, const float* __restrict__ Fvf,
  const float* __restrict__ wv, const float* __restrict__ C0,
  float* __restrict__ To, float* __restrict__ dtA, float* __restrict__ k4t,
  float* __restrict__ pmm, int stage, float cnext)
{
  int i = blockIdx.x * 256 + threadIdx.x;
  int w = i & 63, h = (i >> 6) & 31;
  int bv = i >> 11;
  int v = bv % 13;
  int bvbase = bv * 2048;
  int rb = bvbase + h * 64;
  int bbase = (bv - v) * 2048;
  int hw = h * 64 + w;
  float lat = latOf(h);
  float invpx = 1.0f / (PXCc * cosf(lat));
  float Ti = T[i];
  float dxT = d_xf(T, rb, w, invpx);
  float dyT = d_yf(T, bvbase, h, w);
  float dzT = d_zf(T, bbase, v, hw);
  float mixT = KHc * (dxxf(T, rb, w, invpx) + dyyf(T, bvbase, h, w)) + KVc * dzzf(T, bbase, v, hw);
  float ta = Ti + 273.15f;
  float t2 = ta * ta;
  float ta5 = t2 * t2 * ta;
  float rc = -RCCc * ta5 / cPRS[v];
  float kt = C0[i] - Fu[i] * dxT - Fvf[i] * dyT - wv[i] * dzT + mixT + rc;
  if (stage == 1) dtA[i] = kt;
  else if (stage < 4) dtA[i] += 2.f * kt;
  else {
    float a = dtA[i] + kt; dtA[i] = a; k4t[i] = kt;
    float m0 = blockRed<1>(a), m1 = blockRed<2>(a);
    if (!threadIdx.x){ pmm[blockIdx.x * 2] = m0; pmm[blockIdx.x * 2 + 1] = m1; }
  }
  if (stage < 4) To[i] = t0[i] + cnext * kt;
}

__global__ void __launch_bounds__(64) zt_k(const float* __restrict__ k4t, float* __restrict__ zt, float* __restrict__ pmm)
{
  int col = blockIdx.x * 64 + threadIdx.x;
  int b = col >> 11, p = col & 2047;
  int fb = b * 13 * 2048 + p;
  float cum = 0.f, mn = FBIG, mx = -FBIG;
  #pragma unroll
  for (int v = 0; v < 13; ++v){
    cum += cDZ[v] * (-R_GASc / cPRS[v]) * k4t[fb + v * 2048];
    zt[fb + v * 2048] = cum;
    mn = fminf(mn, cum); mx = fmaxf(mx, cum);
  }
  mn = waveRedMin(mn); mx = waveRedMax(mx);
  if (!threadIdx.x){ pmm[blockIdx.x * 2] = mn; pmm[blockIdx.x * 2 + 1] = mx; }
}

__global__ void __launch_bounds__(256) qt_k(const float* __restrict__ Fq,
  const float* __restrict__ Fu, const float* __restrict__ Fvf,
  const float* __restrict__ wv, const float* __restrict__ prr,
  float* __restrict__ qt, float* __restrict__ pmm)
{
  int i = blockIdx.x * 256 + threadIdx.x;
  int w = i & 63, h = (i >> 6) & 31;
  int bv = i >> 11;
  int v = bv % 13;
  int bvbase = bv * 2048;
  int rb = bvbase + h * 64;
  int bbase = (bv - v) * 2048;
  int hw = h * 64 + w;
  float lat = latOf(h);
  float invpx = 1.0f / (PXCc * cosf(lat));
  float qtv = -Fu[i] * d_xf(Fq, rb, w, invpx) - Fvf[i] * d_yf(Fq, bvbase, h, w) - wv[i] * d_zf(Fq, bbase, v, hw)
            + KHc * (dxxf(Fq, rb, w, invpx) + dyyf(Fq, bvbase, h, w)) + KVc * dzzf(Fq, bbase, v, hw) - prr[i];
  qt[i] = qtv;
  float m0 = blockRed<1>(qtv), m1 = blockRed<2>(qtv);
  if (!threadIdx.x){ pmm[blockIdx.x * 2] = m0; pmm[blockIdx.x * 2 + 1] = m1; }
}

__global__ void __launch_bounds__(256) finalize2_k(const float* __restrict__ pduv,
  const float* __restrict__ pdt, const float* __restrict__ pqt, const float* __restrict__ pzt,
  const float* __restrict__ sc1, float* __restrict__ sc2)
{
  int t = threadIdx.x;
  float dumn = FBIG, dumx = -FBIG, dvmn = FBIG, dvmx = -FBIG, dtmn = FBIG, dtmx = -FBIG;
  float qmn = FBIG, qmx = -FBIG, zmn = FBIG, zmx = -FBIG;
  for (int j = t; j < 832; j += 256){
    dumn = fminf(dumn, pduv[j * 4]);     dumx = fmaxf(dumx, pduv[j * 4 + 1]);
    dvmn = fminf(dvmn, pduv[j * 4 + 2]); dvmx = fmaxf(dvmx, pduv[j * 4 + 3]);
    dtmn = fminf(dtmn, pdt[j * 2]);      dtmx = fmaxf(dtmx, pdt[j * 2 + 1]);
    qmn = fminf(qmn, pqt[j * 2]);        qmx = fmaxf(qmx, pqt[j * 2 + 1]);
  }
  if (t < 256){ zmn = fminf(zmn, pzt[t * 2]); zmx = fmaxf(zmx, pzt[t * 2 + 1]); }
  dumn = blockRed<1>(dumn); dumx = blockRed<2>(dumx);
  dvmn = blockRed<1>(dvmn); dvmx = blockRed<2>(dvmx);
  dtmn = blockRed<1>(dtmn); dtmx = blockRed<2>(dtmx);
  qmn = blockRed<1>(qmn);   qmx = blockRed<2>(qmx);
  zmn = blockRed<1>(zmn);   zmx = blockRed<2>(zmx);
  if (t == 0){
    float rmn[5] = {zmn, qmn, dumn, dvmn, dtmn};
    float rmx[5] = {zmx, qmx, dumx, dvmx, dtmx};
    float cfs[5] = {DT, DT, DT / 6.f, DT / 6.f, DT / 6.f};
    #pragma unroll
    for (int f = 0; f < 5; ++f){
      float mnf = sc1[2 + f * 3], mef = sc1[3 + f * 3], mxf = sc1[4 + f * 3];
      float a = (mnf - mef) * 0.05f, b2 = (mxf - mef) * 0.05f;
      float cf = cfs[f];
      float dmn = rmn[f] * cf, dmx = rmx[f] * cf;
      float s = (b2 - a) / (dmx - dmn);
      sc2[f * 2] = s * cf;
      sc2[f * 2 + 1] = a - dmn * s;
    }
  }
}

__global__ void __launch_bounds__(256) outmid_k(const float* __restrict__ hb,
  const float* __restrict__ Fz, const float* __restrict__ Fq, const float* __restrict__ Fu,
  const float* __restrict__ Fvf, const float* __restrict__ Ft,
  const float* __restrict__ zt, const float* __restrict__ qt,
  const float* __restrict__ duA, const float* __restrict__ dvA, const float* __restrict__ dtA,
  const float* __restrict__ coef, const float* __restrict__ sc2, float* __restrict__ mid)
{
  int e = blockIdx.x * 256 + threadIdx.x;
  int b = e / (65 * 2048);
  int r = e - b * 65 * 2048;
  int c = r >> 11, p = r & 2047;
  int f = c / 13, v = c - f * 13;
  int fi = (b * 13 + v) * 2048 + p;
  const float* Fp; const float* Rp;
  switch (f){
    case 0: Fp = Fz; Rp = zt; break;
    case 1: Fp = Fq; Rp = qt; break;
    case 2: Fp = Fu; Rp = duA; break;
    case 3: Fp = Fvf; Rp = dvA; break;
    default: Fp = Ft; Rp = dtA; break;
  }
  float phys = Fp[fi] + Rp[fi] * sc2[f * 2] + sc2[f * 2 + 1];
  float cf = coef[c * 2048 + p];
  mid[e] = cf * phys + (1.0f - cf) * hb[e];
}

__global__ void __launch_bounds__(256) bn_stats2_k(const float* __restrict__ y,
  const float* __restrict__ g, const float* __restrict__ bb, float* __restrict__ A, float* __restrict__ Bv)
{
  int c = blockIdx.x;
  float s = 0.f, s2 = 0.f;
  for (int j = threadIdx.x; j < 16384; j += 256){
    int b = j >> 11, p = j & 2047;
    float v = y[(size_t)(b * 256 + c) * 2048 + p];
    s += v; s2 += v * v;
  }
  s = blockRed<0>(s);
  s2 = blockRed<0>(s2);
  if (!threadIdx.x){
    float m = s * (1.0f / 16384.0f);
    float var = s2 * (1.0f / 16384.0f) - m * m;
    float rstd = rsqrtf(var + 1e-5f);
    A[c] = g[c] * rstd; Bv[c] = bb[c] - m * g[c] * rstd;
  }
}

__global__ void __launch_bounds__(256) final_k(float* __restrict__ y, const float* __restrict__ x,
  const float* __restrict__ A, const float* __restrict__ Bv)
{
  int e4 = blockIdx.x * 256 + threadIdx.x;
  int c = (e4 >> 9) & 255;
  float4 v = ((const float4*)y)[e4];
  float4 xv = ((const float4*)x)[e4];
  float a = A[c], bb = Bv[c];
  v.x = v.x * a + bb + xv.x;
  v.y = v.y * a + bb + xv.y;
  v.z = v.z * a + bb + xv.z;
  v.w = v.w * a + bb + xv.w;
  ((float4*)y)[e4] = v;
}

extern "C" void kernel_launch(void* const* d_in, const int* in_sizes, int n_in,
                              void* d_out, int out_size, void* d_ws, size_t ws_size,
                              hipStream_t stream)
{
  (void)in_sizes; (void)n_in; (void)out_size; (void)ws_size;
  const float* x        = (const float*)d_in[0];
  const float* w_norm   = (const float*)d_in[1];
  const float* b_norm   = (const float*)d_in[2];
  const float* w_innorm = (const float*)d_in[3];
  const float* b_innorm = (const float*)d_in[4];
  const float* coef     = (const float*)d_in[5];
  GB gb;
  for (int f = 0; f < 5; ++f){
    gb.g[f] = (const float*)d_in[6 + 2 * f];
    gb.b[f] = (const float*)d_in[7 + 2 * f];
  }
  const float* gblk = (const float*)d_in[16];
  const float* bblk = (const float*)d_in[17];
  float* yout = (float*)d_out;

  float* ws = (float*)d_ws;
  size_t off = 0;
  auto alloc = [&](size_t n){ float* p = ws + off; off += n; return p; };
  float* hb  = alloc(NHB);
  float* Fz  = alloc(NF); float* Fq  = alloc(NF); float* Fu  = alloc(NF);
  float* Fvf = alloc(NF); float* Ft  = alloc(NF);
  float* zx  = alloc(NF); float* zy  = alloc(NF); float* zz  = alloc(NF);
  float* ux  = alloc(NF); float* vy  = alloc(NF); float* wvel = alloc(NF);
  float* C0  = alloc(NF); float* prr = alloc(NF);
  float* Ua  = alloc(NF); float* Ub  = alloc(NF); float* Va  = alloc(NF); float* Vb = alloc(NF);
  float* Ta  = alloc(NF); float* Tb  = alloc(NF);
  float* duA = alloc(NF); float* dvA = alloc(NF); float* dtA = alloc(NF);
  float* k4t = alloc(NF); float* ztA = alloc(NF); float* qtA = alloc(NF);
  float* A1 = alloc(65);  float* B1 = alloc(65);
  float* A2 = alloc(256); float* B2 = alloc(256);
  float* sc1 = alloc(32); float* sc2 = alloc(16);
  float* part1 = alloc(256 * 17);
  float* pduv = alloc(832 * 4); float* pdt = alloc(832 * 2);
  float* pqt  = alloc(832 * 2); float* pzt = alloc(256 * 2);
  float* Wp1f = alloc(9 * 80 * 256 / 2);   // bf16 [9][80][256]
  float* Wp2f = alloc(9 * 256 * 96 / 2);   // bf16 [9][256][96]
  unsigned short* Wp1 = (unsigned short*)Wp1f;
  unsigned short* Wp2 = (unsigned short*)Wp2f;
  // XT bf16 [8][32][64][256] = 8,388,608 B, aliases Ua..k4t (10*NF*4 = 8,519,680 B);
  // XT is dead after conv1, long before uv_stage writes Ua.
  unsigned short* XT = (unsigned short*)Ua;
  // MT bf16 [8][32][64][96] = 3,145,728 B, aliases Tb..dtA (3,407,872 B);
  // written by transpose_mid AFTER outmid_k's last read of duA/dvA/dtA.
  unsigned short* MT = (unsigned short*)Tb;
  // mid aliases Ua..Ta (5*NF >= NHB)
  float* mid = Ua;

  transpose_in_k<256, 256><<<dim3(32, 8), 256, 0, stream>>>(x, XT);
  packW_k<<<(9 * 80 * 256 + 255) / 256, 256, 0, stream>>>(w_norm, Wp1, 65, 256, 80, 256);
  packW_k<<<(9 * 256 * 96 + 255) / 256, 256, 0, stream>>>(w_innorm, Wp2, 256, 65, 256, 96);
  conv_mfma_k<256, 128, 65, 80, 5, 1, 7><<<dim3(32, 8), 5 * 64, 0, stream>>>(XT, Wp1, b_norm, hb);
  bn_stats1_k<<<65, 256, 0, stream>>>(hb, gb, A1, B1);
  prep_k<<<NCOL / 64, 64, 0, stream>>>(hb, A1, B1, Fz, Fq, Fu, Fvf, Ft, zx, zy, zz, ux, vy, wvel, part1);
  finalize1_k<<<1, 256, 0, stream>>>(part1, sc1);
  qsC0_k<<<NF / 256, 256, 0, stream>>>(Ft, Fq, zz, wvel, sc1, C0, prr);
  uv_stage_k<<<NF / 256, 256, 0, stream>>>(Fu, Fvf, Fu, Fvf, ux, vy, zx, zy, wvel, Ua, Va, duA, dvA, pduv, 1, 0.5f * DT);
  uv_stage_k<<<NF / 256, 256, 0, stream>>>(Ua, Va, Fu, Fvf, ux, vy, zx, zy, wvel, Ub, Vb, duA, dvA, pduv, 2, 0.5f * DT);
  uv_stage_k<<<NF / 256, 256, 0, stream>>>(Ub, Vb, Fu, Fvf, ux, vy, zx, zy, wvel, Ua, Va, duA, dvA, pduv, 3, DT);
  uv_stage_k<<<NF / 256, 256, 0, stream>>>(Ua, Va, Fu, Fvf, ux, vy, zx, zy, wvel, Ub, Vb, duA, dvA, pduv, 4, 0.f);
  t_stage_k<<<NF / 256, 256, 0, stream>>>(Ft, Ft, Fu, Fvf, wvel, C0, Ta, dtA, k4t, pdt, 1, 0.5f * DT);
  t_stage_k<<<NF / 256, 256, 0, stream>>>(Ta, Ft, Fu, Fvf, wvel, C0, Tb, dtA, k4t, pdt, 2, 0.5f * DT);
  t_stage_k<<<NF / 256, 256, 0, stream>>>(Tb, Ft, Fu, Fvf, wvel, C0, Ta, dtA, k4t, pdt, 3, DT);
  t_stage_k<<<NF / 256, 256, 0, stream>>>(Ta, Ft, Fu, Fvf, wvel, C0, Tb, dtA, k4t, pdt, 4, 0.f);
  zt_k<<<NCOL / 64, 64, 0, stream>>>(k4t, ztA, pzt);
  qt_k<<<NF / 256, 256, 0, stream>>>(Fq, Fu, Fvf, wvel, prr, qtA, pqt);
  finalize2_k<<<1, 256, 0, stream>>>(pduv, pdt, pqt, pzt, sc1, sc2);
  outmid_k<<<NHB / 256, 256, 0, stream>>>(hb, Fz, Fq, Fu, Fvf, Ft, ztA, qtA, duA, dvA, dtA, coef, sc2, mid);
  transpose_in_k<65, 96><<<dim3(32, 8), 256, 0, stream>>>(mid, MT);
  conv_mfma_k<96, 96, 256, 256, 8, 2, 3><<<dim3(32, 8), 8 * 64, 0, stream>>>(MT, Wp2, b_innorm, yout);
  bn_stats2_k<<<256, 256, 0, stream>>>(yout, gblk, bblk, A2, B2);
  final_k<<<4194304 / 4 / 256, 256, 0, stream>>>(yout, x, A2, B2);
}

// Round 3
// 213.074 us; speedup vs baseline: 6.7387x; 1.0881x over previous
//
#include <hip/hip_runtime.h>
#include <math.h>

#define DEVFN static __device__ __forceinline__

static constexpr int BB = 8, VV = 13, HH = 32, WW = 64;
static constexpr int NPLANE = HH * WW;        // 2048
static constexpr int NF = BB * VV * NPLANE;   // 212992
static constexpr int NHB = BB * 65 * NPLANE;  // 1064960
static constexpr int NCOL = BB * NPLANE;      // 16384

static constexpr float DT = 300.0f;
static constexpr float KHc = 15.0f, KVc = 0.1f;
static constexpr float OMEGAc = 7.29e-5f;
static constexpr float L_Vc = 2.5e6f;
static constexpr float R_GASc = 8.314f;
static constexpr float C_Pc = 1005.0f;
static constexpr float PTHc = 0.8f;
static constexpr float PYc  = (float)(3.14159265358979323846 * 6371000.0 / 33.0);
static constexpr float PXCc = (float)(2.0 * 3.14159265358979323846 * 6371000.0 / 64.0);
static constexpr float RCCc = (float)(0.7 * 5.67e-8 * 287.0 / (1005.0 * 100.0));
static constexpr float FBIG = 3.402823466e38f;

__constant__ float cDZ[13]  = {50,50,50,50,50,75,100,100,100,125,112,75,75};
__constant__ float cPRS[13] = {50,100,150,200,250,300,400,500,600,700,850,925,1000};

typedef short bf16x8 __attribute__((ext_vector_type(8)));
typedef float f32x4 __attribute__((ext_vector_type(4)));

DEVFN int pmh(int r){ return r < 0 ? r + 2 : (r > HH - 1 ? r - 2 : r); }
DEVFN int pmv(int r){ return r < 0 ? r + 2 : (r > VV - 1 ? r - 2 : r); }
DEVFN float latOf(int h){ return (90.0f - (float)(h + 1) * (180.0f / 33.0f)) * 0.017453292519943295f; }
DEVFN float avoid_inf(float t){
  if (t == 0.0f) t = 0.1f;
  if (fabsf(t) < 1.0f) t = copysignf(1.0f, t);
  return t;
}
DEVFN unsigned short f2bf(float f){
  unsigned u = __float_as_uint(f);
  unsigned r = (u + 0x7fffu + ((u >> 16) & 1u)) >> 16;
  return (unsigned short)r;
}

// ---- stencils on a field laid out [B][13][32][64] ----
DEVFN float d_xf(const float* __restrict__ F, int rb, int w, float invpx){
  return (F[rb + ((w + 62) & 63)] - 8.f * F[rb + ((w + 63) & 63)]
        + 8.f * F[rb + ((w + 1) & 63)] - F[rb + ((w + 2) & 63)]) * (1.f / 12.f) * invpx;
}
DEVFN float d_yf(const float* __restrict__ F, int bvbase, int h, int w){
  return (-F[bvbase + pmh(h - 2) * 64 + w] + 8.f * F[bvbase + pmh(h - 1) * 64 + w]
          - 8.f * F[bvbase + pmh(h + 1) * 64 + w] + F[bvbase + pmh(h + 2) * 64 + w]) * (1.f / 12.f) * (1.f / PYc);
}
DEVFN float d_zf(const float* __restrict__ F, int bbase, int v, int hw){
  return (-F[bbase + pmv(v - 2) * 2048 + hw] + 8.f * F[bbase + pmv(v - 1) * 2048 + hw]
          - 8.f * F[bbase + pmv(v + 1) * 2048 + hw] + F[bbase + pmv(v + 2) * 2048 + hw]) * (1.f / 12.f) / cDZ[v];
}
DEVFN float dxxf(const float* __restrict__ F, int rb, int w, float invpx){
  float s = F[rb + ((w + 60) & 63)] - 16.f * F[rb + ((w + 61) & 63)] + 64.f * F[rb + ((w + 62) & 63)]
          + 16.f * F[rb + ((w + 63) & 63)] - 130.f * F[rb + w] + 16.f * F[rb + ((w + 1) & 63)]
          + 64.f * F[rb + ((w + 2) & 63)] - 16.f * F[rb + ((w + 3) & 63)] + F[rb + ((w + 4) & 63)];
  return s * (1.f / 144.f) * invpx * invpx;
}
DEVFN float dyyf(const float* __restrict__ F, int bvbase, int h, int w){
  float g0 = d_yf(F, bvbase, pmh(h - 2), w);
  float g1 = d_yf(F, bvbase, pmh(h - 1), w);
  float g2 = d_yf(F, bvbase, pmh(h + 1), w);
  float g3 = d_yf(F, bvbase, pmh(h + 2), w);
  return (-g0 + 8.f * g1 - 8.f * g2 + g3) * (1.f / 12.f) * (1.f / PYc);
}
DEVFN float dzzf(const float* __restrict__ F, int bbase, int v, int hw){
  float g0 = d_zf(F, bbase, pmv(v - 2), hw);
  float g1 = d_zf(F, bbase, pmv(v - 1), hw);
  float g2 = d_zf(F, bbase, pmv(v + 1), hw);
  float g3 = d_zf(F, bbase, pmv(v + 2), hw);
  return (-g0 + 8.f * g1 - 8.f * g2 + g3) * (1.f / 12.f) / cDZ[v];
}

// ---- reductions ----
DEVFN float waveRedSum(float v){ for (int o = 32; o; o >>= 1) v += __shfl_down(v, o, 64); return v; }
DEVFN float waveRedMin(float v){ for (int o = 32; o; o >>= 1) v = fminf(v, __shfl_down(v, o, 64)); return v; }
DEVFN float waveRedMax(float v){ for (int o = 32; o; o >>= 1) v = fmaxf(v, __shfl_down(v, o, 64)); return v; }

template<int OP>
static __device__ float blockRed(float v){
  __shared__ float s[4];
  v = OP == 0 ? waveRedSum(v) : OP == 1 ? waveRedMin(v) : waveRedMax(v);
  int lane = threadIdx.x & 63, wid = threadIdx.x >> 6;
  __syncthreads();
  if (lane == 0) s[wid] = v;
  __syncthreads();
  float r;
  if (OP == 0) r = s[0] + s[1] + s[2] + s[3];
  else if (OP == 1) r = fminf(fminf(s[0], s[1]), fminf(s[2], s[3]));
  else r = fmaxf(fmaxf(s[0], s[1]), fmaxf(s[2], s[3]));
  return r;
}

// ================= conv via MFMA =================
// transpose [B][CI][32][64] f32 -> [B][32][64][CIT] bf16; grid.z splits the ci-phases
template<int CI, int CIT, int PH>
__global__ void __launch_bounds__(256) transpose_in_k(const float* __restrict__ x,
    unsigned short* __restrict__ XT)
{
  __shared__ float tile[16 * 68];
  int h = blockIdx.x, b = blockIdx.y;
  int t = threadIdx.x;
  int p0 = blockIdx.z * PH;
  for (int p = p0; p < p0 + PH; ++p){
    int cbase = p * 16;
    __syncthreads();
    {
      int cl = t >> 4, w4 = (t & 15) * 4;
      int ci = cbase + cl;
      float4 v = make_float4(0.f, 0.f, 0.f, 0.f);
      if (ci < CI) v = *(const float4*)(x + (((size_t)(b * CI + ci) * 32 + h) * 64 + w4));
      tile[cl * 68 + w4 + 0] = v.x; tile[cl * 68 + w4 + 1] = v.y;
      tile[cl * 68 + w4 + 2] = v.z; tile[cl * 68 + w4 + 3] = v.w;
    }
    __syncthreads();
    {
      int w = t >> 2, c4 = (t & 3) * 4;
      ushort4 o;
      o.x = f2bf(tile[(c4 + 0) * 68 + w]);
      o.y = f2bf(tile[(c4 + 1) * 68 + w]);
      o.z = f2bf(tile[(c4 + 2) * 68 + w]);
      o.w = f2bf(tile[(c4 + 3) * 68 + w]);
      *(ushort4*)(XT + (((size_t)(b * 32 + h) * 64 + w) * CIT + cbase + c4)) = o;
    }
  }
}

// both weight tensors packed in one launch
__global__ void __launch_bounds__(256) packW2_k(const float* __restrict__ w1,
    const float* __restrict__ w2, unsigned short* __restrict__ wp1, unsigned short* __restrict__ wp2)
{
  const int T1 = 9 * 80 * 256;
  const int T2 = 9 * 256 * 96;
  int idx = blockIdx.x * 256 + threadIdx.x;
  if (idx < T1){
    int dir = idx / (80 * 256);
    int r = idx - dir * (80 * 256);
    int co = r / 256, ci = r - co * 256;
    float v = (co < 65) ? w1[((size_t)(co * 256 + ci)) * 9 + dir] : 0.f;
    wp1[idx] = f2bf(v);
  } else if (idx < T1 + T2){
    int j = idx - T1;
    int dir = j / (256 * 96);
    int r = j - dir * (256 * 96);
    int co = r / 96, ci = r - co * 96;
    float v = (ci < 65) ? w2[((size_t)(co * 65 + ci)) * 9 + dir] : 0.f;
    wp2[j] = f2bf(v);
  }
}

// Implicit-GEMM conv3x3 (zero pad). Block = one (b,h) row of 64 pixels.
template<int CIT, int CIL, int CO, int COp, int NW, int MF, int SWZ>
__global__ void __launch_bounds__(NW * 64) conv_mfma_k(
    const unsigned short* __restrict__ XT, const unsigned short* __restrict__ Wp,
    const float* __restrict__ bias, float* __restrict__ out)
{
  __shared__ __align__(16) unsigned short Xl[3 * 66 * CIL];
  const int C8 = CIL / 8;
  int tid = threadIdx.x;
  int h = blockIdx.x, b = blockIdx.y;
  int wid = tid >> 6, lane = tid & 63;
  int l15 = lane & 15, q = lane >> 4;

  f32x4 acc[MF][4];
  #pragma unroll
  for (int mf = 0; mf < MF; ++mf)
    #pragma unroll
    for (int nf = 0; nf < 4; ++nf){ f32x4 z = {0.f, 0.f, 0.f, 0.f}; acc[mf][nf] = z; }

  for (int cp = 0; cp < CIT / CIL; ++cp){
    if (cp) __syncthreads();
    for (int idx = tid; idx < 3 * 64 * C8; idx += NW * 64){
      int r = idx / (64 * C8);
      int rest = idx - r * 64 * C8;
      int j1 = rest / C8;
      int c8 = rest - j1 * C8;
      int j = j1 + 1;
      int hh = h + r - 1;
      uint4 val = make_uint4(0, 0, 0, 0);
      if (hh >= 0 && hh < 32)
        val = *(const uint4*)(XT + (((size_t)(b * 32 + hh) * 64 + j1) * CIT + cp * CIL + c8 * 8));
      int dst = (r * 66 + j) * CIL + ((c8 * 8) ^ ((j & SWZ) << 3));
      *(uint4*)(Xl + dst) = val;
    }
    for (int idx = tid; idx < 3 * 2 * C8; idx += NW * 64){
      int r = idx / (2 * C8);
      int rest = idx - r * 2 * C8;
      int js = rest / C8;
      int c8 = rest - js * C8;
      int j = js ? 65 : 0;
      int dst = (r * 66 + j) * CIL + ((c8 * 8) ^ ((j & SWZ) << 3));
      *(uint4*)(Xl + dst) = make_uint4(0, 0, 0, 0);
    }
    __syncthreads();

    for (int dir = 0; dir < 9; ++dir){
      int dy = dir / 3, dx = dir - dy * 3;
      #pragma unroll
      for (int kc = 0; kc < CIL / 32; ++kc){
        int kb = kc * 32 + q * 8;
        bf16x8 a[MF];
        #pragma unroll
        for (int mf = 0; mf < MF; ++mf){
          int co = wid * (MF * 16) + mf * 16 + l15;
          a[mf] = *(const bf16x8*)(Wp + ((size_t)(dir * COp + co) * CIT + cp * CIL + kb));
        }
        #pragma unroll
        for (int nf = 0; nf < 4; ++nf){
          int j = nf * 16 + l15 + dx;
          bf16x8 bfrag = *(const bf16x8*)(Xl + ((dy * 66 + j) * CIL + (kb ^ ((j & SWZ) << 3))));
          #pragma unroll
          for (int mf = 0; mf < MF; ++mf)
            acc[mf][nf] = __builtin_amdgcn_mfma_f32_16x16x32_bf16(a[mf], bfrag, acc[mf][nf], 0, 0, 0);
        }
      }
    }
  }
  #pragma unroll
  for (int mf = 0; mf < MF; ++mf){
    #pragma unroll
    for (int r = 0; r < 4; ++r){
      int co = wid * (MF * 16) + mf * 16 + q * 4 + r;
      if (CO != COp && co >= CO) continue;
      float bv = bias[co];
      #pragma unroll
      for (int nf = 0; nf < 4; ++nf){
        int pix = nf * 16 + l15;
        out[(size_t)(b * CO + co) * 2048 + h * 64 + pix] = acc[mf][nf][r] + bv;
      }
    }
  }
}

// ================= BN stats =================
struct GB { const float* g[5]; const float* b[5]; };

__global__ void __launch_bounds__(256) bn_stats1_k(const float* __restrict__ x, GB gb,
    float* __restrict__ A, float* __restrict__ Bv)
{
  int c = blockIdx.x;
  float s = 0.f, s2 = 0.f;
  for (int j = threadIdx.x; j < 16384; j += 256){
    int b = j >> 11, p = j & 2047;
    float v = x[(size_t)(b * 65 + c) * NPLANE + p];
    s += v; s2 += v * v;
  }
  s = blockRed<0>(s);
  s2 = blockRed<0>(s2);
  if (threadIdx.x == 0){
    float m = s * (1.0f / 16384.0f);
    float var = s2 * (1.0f / 16384.0f) - m * m;
    float rstd = rsqrtf(var + 1e-5f);
    int f = c / 13, k = c - f * 13;
    float g = gb.g[f][k], bb = gb.b[f][k];
    A[c] = g * rstd; Bv[c] = bb - m * g * rstd;
  }
}

__global__ void __launch_bounds__(64) prep_k(const float* __restrict__ hb,
  const float* __restrict__ A, const float* __restrict__ Bv,
  float* __restrict__ Fz, float* __restrict__ Fq, float* __restrict__ Fu,
  float* __restrict__ Fvf, float* __restrict__ Ft,
  float* __restrict__ zx, float* __restrict__ zy, float* __restrict__ zz,
  float* __restrict__ ux, float* __restrict__ vy, float* __restrict__ wv,
  float* __restrict__ part)
{
  int col = blockIdx.x * 64 + threadIdx.x;
  int b = col >> 11, p = col & 2047, h = p >> 6, w = p & 63;
  int hbase = b * 65 * NPLANE;
  auto hn = [&](int ch, int hh, int ww)->float {
    return hb[hbase + ch * NPLANE + hh * 64 + ww] * A[ch] + Bv[ch];
  };
  float zc[13], qc[13], uc[13], vc[13], tc[13];
  #pragma unroll
  for (int v = 0; v < 13; ++v){
    zc[v] = hn(v, h, w); qc[v] = hn(13 + v, h, w); uc[v] = hn(26 + v, h, w);
    vc[v] = hn(39 + v, h, w); tc[v] = hn(52 + v, h, w);
  }
  int fb = (b * 13) * 2048 + p;
  #pragma unroll
  for (int v = 0; v < 13; ++v){
    int fi = fb + v * 2048;
    Fz[fi] = zc[v]; Fq[fi] = qc[v]; Fu[fi] = uc[v]; Fvf[fi] = vc[v]; Ft[fi] = tc[v];
    zz[fi] = (-zc[pmv(v - 2)] + 8.f * zc[pmv(v - 1)] - 8.f * zc[pmv(v + 1)] + zc[pmv(v + 2)]) * (1.f / 12.f) / cDZ[v];
  }
  float lat = latOf(h);
  float invpx = 1.0f / (PXCc * cosf(lat));
  int wm2 = (w + 62) & 63, wm1 = (w + 63) & 63, wp1 = (w + 1) & 63, wp2 = (w + 2) & 63;
  int hm2 = pmh(h - 2), hm1 = pmh(h - 1), hp1 = pmh(h + 1), hp2 = pmh(h + 2);
  float cum = 0.f;
  #pragma unroll
  for (int v = 0; v < 13; ++v){
    int fi = fb + v * 2048;
    float zxv = (hn(v, h, wm2) - 8.f * hn(v, h, wm1) + 8.f * hn(v, h, wp1) - hn(v, h, wp2)) * (1.f / 12.f) * invpx;
    float zyv = (-hn(v, hm2, w) + 8.f * hn(v, hm1, w) - 8.f * hn(v, hp1, w) + hn(v, hp2, w)) * (1.f / 12.f) * (1.f / PYc);
    float uxv = (hn(26 + v, h, wm2) - 8.f * hn(26 + v, h, wm1) + 8.f * hn(26 + v, h, wp1) - hn(26 + v, h, wp2)) * (1.f / 12.f) * invpx;
    float vyv = (-hn(39 + v, hm2, w) + 8.f * hn(39 + v, hm1, w) - 8.f * hn(39 + v, hp1, w) + hn(39 + v, hp2, w)) * (1.f / 12.f) * (1.f / PYc);
    zx[fi] = zxv; zy[fi] = zyv; ux[fi] = uxv; vy[fi] = vyv;
    cum += cDZ[v] * (uxv + vyv);
    wv[fi] = -cum;
  }
  float smn = FBIG, smx = -FBIG;
  #pragma unroll
  for (int v = 0; v < 13; ++v){
    float tcc = tc[v] - 273.15f;
    float a = 17.67f * tcc / avoid_inf(tcc + 243.5f);
    smn = fminf(smn, a); smx = fmaxf(smx, a);
  }
  float fmn[5], fmx[5], fsm[5];
  #pragma unroll
  for (int f = 0; f < 5; ++f){
    const float* cc = f == 0 ? zc : f == 1 ? qc : f == 2 ? uc : f == 3 ? vc : tc;
    float mn = cc[0], mx = cc[0], sm = 0.f;
    #pragma unroll
    for (int v = 0; v < 13; ++v){ mn = fminf(mn, cc[v]); mx = fmaxf(mx, cc[v]); sm += cc[v]; }
    fmn[f] = mn; fmx[f] = mx; fsm[f] = sm;
  }
  float r;
  float* pb = part + blockIdx.x * 17;
  r = waveRedMin(smn); if (!threadIdx.x) pb[0] = r;
  r = waveRedMax(smx); if (!threadIdx.x) pb[1] = r;
  #pragma unroll
  for (int f = 0; f < 5; ++f){
    r = waveRedMin(fmn[f]); if (!threadIdx.x) pb[2 + f * 3] = r;
    r = waveRedMax(fmx[f]); if (!threadIdx.x) pb[3 + f * 3] = r;
    r = waveRedSum(fsm[f]); if (!threadIdx.x) pb[4 + f * 3] = r;
  }
}

__global__ void __launch_bounds__(256) finalize1_k(const float* __restrict__ part, float* __restrict__ sc1)
{
  int t = threadIdx.x;
  const float* pr = part + t * 17;
  float smn = blockRed<1>(pr[0]);
  float smx = blockRed<2>(pr[1]);
  float st[15];
  #pragma unroll
  for (int f = 0; f < 5; ++f){
    st[f * 3 + 0] = blockRed<1>(pr[2 + f * 3]);
    st[f * 3 + 1] = blockRed<2>(pr[3 + f * 3]);
    st[f * 3 + 2] = blockRed<0>(pr[4 + f * 3]);
  }
  if (t == 0){
    float ss = (3.01f + 3.47f) / (smx - smn);
    sc1[0] = ss; sc1[1] = -3.47f - smn * ss;
    #pragma unroll
    for (int f = 0; f < 5; ++f){
      sc1[2 + f * 3 + 0] = st[f * 3 + 0];
      sc1[2 + f * 3 + 1] = st[f * 3 + 2] * (1.0f / (float)NF);
      sc1[2 + f * 3 + 2] = st[f * 3 + 1];
    }
  }
}

// ===== merged RK stage: u,v,t (+C0/prr at stage1, +q-tendency at stage2) =====
template<int STAGE>
__global__ void __launch_bounds__(256) stage_k(
  const float* U, const float* Vf, const float* T,
  const float* Fu, const float* Fvf, const float* Ft, const float* Fq,
  const float* ux, const float* vy, const float* zx, const float* zy,
  const float* wv, const float* zz, const float* sc1,
  float* C0, float* prr,
  float* Uo, float* Vo, float* To,
  float* duA, float* dvA, float* dtA, float* k4t, float* qtA,
  float* pduv, float* pdt, float* pqt, float cnext)
{
  int i = blockIdx.x * 256 + threadIdx.x;
  int w = i & 63, h = (i >> 6) & 31;
  int bv = i >> 11;
  int v = bv % 13;
  int bvbase = bv * 2048;
  int rb = bvbase + h * 64;
  int bbase = (bv - v) * 2048;
  int hw = h * 64 + w;
  float lat = latOf(h);
  float invpx = 1.0f / (PXCc * cosf(lat));
  float fcor = 2.0f * OMEGAc * sinf(lat);
  float wvi = wv[i];
  float Ui = U[i], Vi = Vf[i], Ti = T[i];
  float Fui = (STAGE == 1) ? Ui : Fu[i];
  float Fvi = (STAGE == 1) ? Vi : Fvf[i];

  // --- u,v tendencies ---
  float dyU = d_yf(U, bvbase, h, w);
  float dzU = d_zf(U, bbase, v, hw);
  float dxV = d_xf(Vf, rb, w, invpx);
  float dzV = d_zf(Vf, bbase, v, hw);
  float mixU = KHc * (dxxf(U, rb, w, invpx) + dyyf(U, bvbase, h, w)) + KVc * dzzf(U, bbase, v, hw);
  float mixV = KHc * (dxxf(Vf, rb, w, invpx) + dyyf(Vf, bvbase, h, w)) + KVc * dzzf(Vf, bbase, v, hw);
  float ku = -Ui * ux[i] - Vi * dyU - wvi * dzU + fcor * Vi - zx[i] + mixU;
  float kv = -Ui * dxV - Vi * vy[i] - wvi * dzV - fcor * Ui - zy[i] + mixV;

  // --- C0 (physics forcing, stage-independent) ---
  float C0i;
  if (STAGE == 1){
    float zzi = zz[i], qi = Fq[i];
    float rho = -1.0f / avoid_inf(zzi);
    float p = rho * R_GASc * Ti;               // Ti == Ft at stage 1
    float tcc = Ti - 273.15f;
    float arg = 17.67f * tcc / avoid_inf(tcc + 243.5f);
    float es = 6.112f * expf(arg * sc1[0] + sc1[1]) * 100.0f;
    float qs = fmaxf(0.622f * es / avoid_inf(p - 0.378f * es), 1e-6f);
    float rh = qi / avoid_inf(qs);
    float rate = (rh > PTHc) ? (qi - PTHc * qs) * (1.0f / DT) : 0.0f;
    prr[i] = rate;
    C0i = -(L_Vc + 1.0f) * zzi * wvi * (1.0f / C_Pc) + rate * (L_Vc / C_Pc);
    C0[i] = C0i;
  } else {
    C0i = C0[i];
  }

  // --- t tendency ---
  float dxT = d_xf(T, rb, w, invpx);
  float dyT = d_yf(T, bvbase, h, w);
  float dzT = d_zf(T, bbase, v, hw);
  float mixT = KHc * (dxxf(T, rb, w, invpx) + dyyf(T, bvbase, h, w)) + KVc * dzzf(T, bbase, v, hw);
  float ta = Ti + 273.15f;
  float t2 = ta * ta;
  float ta5 = t2 * t2 * ta;
  float rc = -RCCc * ta5 / cPRS[v];
  float kt = C0i - Fui * dxT - Fvi * dyT - wvi * dzT + mixT + rc;

  // --- accumulate ---
  if (STAGE == 1){ duA[i] = ku; dvA[i] = kv; dtA[i] = kt; }
  else if (STAGE < 4){ duA[i] += 2.f * ku; dvA[i] += 2.f * kv; dtA[i] += 2.f * kt; }
  else {
    float au = duA[i] + ku, av = dvA[i] + kv, at = dtA[i] + kt;
    duA[i] = au; dvA[i] = av; dtA[i] = at; k4t[i] = kt;
    float m0 = blockRed<1>(au), m1 = blockRed<2>(au);
    float m2 = blockRed<1>(av), m3 = blockRed<2>(av);
    float m4 = blockRed<1>(at), m5 = blockRed<2>(at);
    if (!threadIdx.x){
      float* pp = pduv + blockIdx.x * 4;
      pp[0] = m0; pp[1] = m1; pp[2] = m2; pp[3] = m3;
      pdt[blockIdx.x * 2] = m4; pdt[blockIdx.x * 2 + 1] = m5;
    }
  }
  if (STAGE < 4){
    float Fti = (STAGE == 1) ? Ti : Ft[i];
    Uo[i] = Fui + cnext * ku;
    Vo[i] = Fvi + cnext * kv;
    To[i] = Fti + cnext * kt;
  }

  // --- q tendency (independent of RK; done once, at stage 2) ---
  if (STAGE == 2){
    float qtv = -Fui * d_xf(Fq, rb, w, invpx) - Fvi * d_yf(Fq, bvbase, h, w) - wvi * d_zf(Fq, bbase, v, hw)
              + KHc * (dxxf(Fq, rb, w, invpx) + dyyf(Fq, bvbase, h, w)) + KVc * dzzf(Fq, bbase, v, hw) - prr[i];
    qtA[i] = qtv;
    float m0 = blockRed<1>(qtv), m1 = blockRed<2>(qtv);
    if (!threadIdx.x){ pqt[blockIdx.x * 2] = m0; pqt[blockIdx.x * 2 + 1] = m1; }
  }
}

__global__ void __launch_bounds__(64) zt_k(const float* __restrict__ k4t, float* __restrict__ zt, float* __restrict__ pmm)
{
  int col = blockIdx.x * 64 + threadIdx.x;
  int b = col >> 11, p = col & 2047;
  int fb = b * 13 * 2048 + p;
  float cum = 0.f, mn = FBIG, mx = -FBIG;
  #pragma unroll
  for (int v = 0; v < 13; ++v){
    cum += cDZ[v] * (-R_GASc / cPRS[v]) * k4t[fb + v * 2048];
    zt[fb + v * 2048] = cum;
    mn = fminf(mn, cum); mx = fmaxf(mx, cum);
  }
  mn = waveRedMin(mn); mx = waveRedMax(mx);
  if (!threadIdx.x){ pmm[blockIdx.x * 2] = mn; pmm[blockIdx.x * 2 + 1] = mx; }
}

__global__ void __launch_bounds__(256) finalize2_k(const float* __restrict__ pduv,
  const float* __restrict__ pdt, const float* __restrict__ pqt, const float* __restrict__ pzt,
  const float* __restrict__ sc1, float* __restrict__ sc2)
{
  int t = threadIdx.x;
  float dumn = FBIG, dumx = -FBIG, dvmn = FBIG, dvmx = -FBIG, dtmn = FBIG, dtmx = -FBIG;
  float qmn = FBIG, qmx = -FBIG, zmn = FBIG, zmx = -FBIG;
  for (int j = t; j < 832; j += 256){
    dumn = fminf(dumn, pduv[j * 4]);     dumx = fmaxf(dumx, pduv[j * 4 + 1]);
    dvmn = fminf(dvmn, pduv[j * 4 + 2]); dvmx = fmaxf(dvmx, pduv[j * 4 + 3]);
    dtmn = fminf(dtmn, pdt[j * 2]);      dtmx = fmaxf(dtmx, pdt[j * 2 + 1]);
    qmn = fminf(qmn, pqt[j * 2]);        qmx = fmaxf(qmx, pqt[j * 2 + 1]);
  }
  if (t < 256){ zmn = fminf(zmn, pzt[t * 2]); zmx = fmaxf(zmx, pzt[t * 2 + 1]); }
  dumn = blockRed<1>(dumn); dumx = blockRed<2>(dumx);
  dvmn = blockRed<1>(dvmn); dvmx = blockRed<2>(dvmx);
  dtmn = blockRed<1>(dtmn); dtmx = blockRed<2>(dtmx);
  qmn = blockRed<1>(qmn);   qmx = blockRed<2>(qmx);
  zmn = blockRed<1>(zmn);   zmx = blockRed<2>(zmx);
  if (t == 0){
    float rmn[5] = {zmn, qmn, dumn, dvmn, dtmn};
    float rmx[5] = {zmx, qmx, dumx, dvmx, dtmx};
    float cfs[5] = {DT, DT, DT / 6.f, DT / 6.f, DT / 6.f};
    #pragma unroll
    for (int f = 0; f < 5; ++f){
      float mnf = sc1[2 + f * 3], mef = sc1[3 + f * 3], mxf = sc1[4 + f * 3];
      float a = (mnf - mef) * 0.05f, b2 = (mxf - mef) * 0.05f;
      float cf = cfs[f];
      float dmn = rmn[f] * cf, dmx = rmx[f] * cf;
      float s = (b2 - a) / (dmx - dmn);
      sc2[f * 2] = s * cf;
      sc2[f * 2 + 1] = a - dmn * s;
    }
  }
}

__global__ void __launch_bounds__(256) outmid_k(const float* __restrict__ hb,
  const float* __restrict__ Fz, const float* __restrict__ Fq, const float* __restrict__ Fu,
  const float* __restrict__ Fvf, const float* __restrict__ Ft,
  const float* __restrict__ zt, const float* __restrict__ qt,
  const float* __restrict__ duA, const float* __restrict__ dvA, const float* __restrict__ dtA,
  const float* __restrict__ coef, const float* __restrict__ sc2, float* __restrict__ mid)
{
  int e = blockIdx.x * 256 + threadIdx.x;
  int b = e / (65 * 2048);
  int r = e - b * 65 * 2048;
  int c = r >> 11, p = r & 2047;
  int f = c / 13, v = c - f * 13;
  int fi = (b * 13 + v) * 2048 + p;
  const float* Fp; const float* Rp;
  switch (f){
    case 0: Fp = Fz; Rp = zt; break;
    case 1: Fp = Fq; Rp = qt; break;
    case 2: Fp = Fu; Rp = duA; break;
    case 3: Fp = Fvf; Rp = dvA; break;
    default: Fp = Ft; Rp = dtA; break;
  }
  float phys = Fp[fi] + Rp[fi] * sc2[f * 2] + sc2[f * 2 + 1];
  float cf = coef[c * 2048 + p];
  mid[e] = cf * phys + (1.0f - cf) * hb[e];
}

__global__ void __launch_bounds__(256) bn_stats2_k(const float* __restrict__ y,
  const float* __restrict__ g, const float* __restrict__ bb, float* __restrict__ A, float* __restrict__ Bv)
{
  int c = blockIdx.x;
  float s = 0.f, s2 = 0.f;
  for (int j = threadIdx.x; j < 16384; j += 256){
    int b = j >> 11, p = j & 2047;
    float v = y[(size_t)(b * 256 + c) * 2048 + p];
    s += v; s2 += v * v;
  }
  s = blockRed<0>(s);
  s2 = blockRed<0>(s2);
  if (!threadIdx.x){
    float m = s * (1.0f / 16384.0f);
    float var = s2 * (1.0f / 16384.0f) - m * m;
    float rstd = rsqrtf(var + 1e-5f);
    A[c] = g[c] * rstd; Bv[c] = bb[c] - m * g[c] * rstd;
  }
}

__global__ void __launch_bounds__(256) final_k(float* __restrict__ y, const float* __restrict__ x,
  const float* __restrict__ A, const float* __restrict__ Bv)
{
  int e4 = blockIdx.x * 256 + threadIdx.x;
  int c = (e4 >> 9) & 255;
  float4 v = ((const float4*)y)[e4];
  float4 xv = ((const float4*)x)[e4];
  float a = A[c], bb = Bv[c];
  v.x = v.x * a + bb + xv.x;
  v.y = v.y * a + bb + xv.y;
  v.z = v.z * a + bb + xv.z;
  v.w = v.w * a + bb + xv.w;
  ((float4*)y)[e4] = v;
}

extern "C" void kernel_launch(void* const* d_in, const int* in_sizes, int n_in,
                              void* d_out, int out_size, void* d_ws, size_t ws_size,
                              hipStream_t stream)
{
  (void)in_sizes; (void)n_in; (void)out_size; (void)ws_size;
  const float* x        = (const float*)d_in[0];
  const float* w_norm   = (const float*)d_in[1];
  const float* b_norm   = (const float*)d_in[2];
  const float* w_innorm = (const float*)d_in[3];
  const float* b_innorm = (const float*)d_in[4];
  const float* coef     = (const float*)d_in[5];
  GB gb;
  for (int f = 0; f < 5; ++f){
    gb.g[f] = (const float*)d_in[6 + 2 * f];
    gb.b[f] = (const float*)d_in[7 + 2 * f];
  }
  const float* gblk = (const float*)d_in[16];
  const float* bblk = (const float*)d_in[17];
  float* yout = (float*)d_out;

  float* ws = (float*)d_ws;
  size_t off = 0;
  auto alloc = [&](size_t n){ float* p = ws + off; off += n; return p; };
  float* hb  = alloc(NHB);
  float* Fz  = alloc(NF); float* Fq  = alloc(NF); float* Fu  = alloc(NF);
  float* Fvf = alloc(NF); float* Ft  = alloc(NF);
  float* zx  = alloc(NF); float* zy  = alloc(NF); float* zz  = alloc(NF);
  float* ux  = alloc(NF); float* vy  = alloc(NF); float* wvel = alloc(NF);
  float* C0  = alloc(NF); float* prr = alloc(NF);
  float* Ua  = alloc(NF); float* Ub  = alloc(NF); float* Va  = alloc(NF); float* Vb = alloc(NF);
  float* Ta  = alloc(NF); float* Tb  = alloc(NF);
  float* duA = alloc(NF); float* dvA = alloc(NF); float* dtA = alloc(NF);
  float* k4t = alloc(NF); float* ztA = alloc(NF); float* qtA = alloc(NF);
  float* A1 = alloc(65);  float* B1 = alloc(65);
  float* A2 = alloc(256); float* B2 = alloc(256);
  float* sc1 = alloc(32); float* sc2 = alloc(16);
  float* part1 = alloc(256 * 17);
  float* pduv = alloc(832 * 4); float* pdt = alloc(832 * 2);
  float* pqt  = alloc(832 * 2); float* pzt = alloc(256 * 2);
  float* Wp1f = alloc(9 * 80 * 256 / 2);   // bf16 [9][80][256]
  float* Wp2f = alloc(9 * 256 * 96 / 2);   // bf16 [9][256][96]
  unsigned short* Wp1 = (unsigned short*)Wp1f;
  unsigned short* Wp2 = (unsigned short*)Wp2f;
  // XT bf16 [8][32][64][256] aliases Ua..k4t; dead before stage1 writes Ua.
  unsigned short* XT = (unsigned short*)Ua;
  // MT bf16 [8][32][64][96] aliases Tb..dtA; written after outmid's last read of duA/dvA/dtA.
  unsigned short* MT = (unsigned short*)Tb;
  // mid aliases Ua..Ta (5*NF == NHB)
  float* mid = Ua;

  transpose_in_k<256, 256, 4><<<dim3(32, 8, 4), 256, 0, stream>>>(x, XT);
  packW2_k<<<(9 * 80 * 256 + 9 * 256 * 96 + 255) / 256, 256, 0, stream>>>(w_norm, w_innorm, Wp1, Wp2);
  conv_mfma_k<256, 128, 65, 80, 5, 1, 7><<<dim3(32, 8), 5 * 64, 0, stream>>>(XT, Wp1, b_norm, hb);
  bn_stats1_k<<<65, 256, 0, stream>>>(hb, gb, A1, B1);
  prep_k<<<NCOL / 64, 64, 0, stream>>>(hb, A1, B1, Fz, Fq, Fu, Fvf, Ft, zx, zy, zz, ux, vy, wvel, part1);
  finalize1_k<<<1, 256, 0, stream>>>(part1, sc1);
  // merged RK stages (u,v,t together; stage1 computes C0/prr; stage2 adds q-tendency)
  stage_k<1><<<NF / 256, 256, 0, stream>>>(Fu, Fvf, Ft, Fu, Fvf, Ft, Fq, ux, vy, zx, zy, wvel, zz, sc1,
      C0, prr, Ua, Va, Ta, duA, dvA, dtA, k4t, qtA, pduv, pdt, pqt, 0.5f * DT);
  stage_k<2><<<NF / 256, 256, 0, stream>>>(Ua, Va, Ta, Fu, Fvf, Ft, Fq, ux, vy, zx, zy, wvel, zz, sc1,
      C0, prr, Ub, Vb, Tb, duA, dvA, dtA, k4t, qtA, pduv, pdt, pqt, 0.5f * DT);
  stage_k<3><<<NF / 256, 256, 0, stream>>>(Ub, Vb, Tb, Fu, Fvf, Ft, Fq, ux, vy, zx, zy, wvel, zz, sc1,
      C0, prr, Ua, Va, Ta, duA, dvA, dtA, k4t, qtA, pduv, pdt, pqt, DT);
  stage_k<4><<<NF / 256, 256, 0, stream>>>(Ua, Va, Ta, Fu, Fvf, Ft, Fq, ux, vy, zx, zy, wvel, zz, sc1,
      C0, prr, Ub, Vb, Tb, duA, dvA, dtA, k4t, qtA, pduv, pdt, pqt, 0.f);
  zt_k<<<NCOL / 64, 64, 0, stream>>>(k4t, ztA, pzt);
  finalize2_k<<<1, 256, 0, stream>>>(pduv, pdt, pqt, pzt, sc1, sc2);
  outmid_k<<<NHB / 256, 256, 0, stream>>>(hb, Fz, Fq, Fu, Fvf, Ft, ztA, qtA, duA, dvA, dtA, coef, sc2, mid);
  transpose_in_k<65, 96, 2><<<dim3(32, 8, 3), 256, 0, stream>>>(mid, MT);
  conv_mfma_k<96, 96, 256, 256, 8, 2, 3><<<dim3(32, 8), 8 * 64, 0, stream>>>(MT, Wp2, b_innorm, yout);
  bn_stats2_k<<<256, 256, 0, stream>>>(yout, gblk, bblk, A2, B2);
  final_k<<<4194304 / 4 / 256, 256, 0, stream>>>(yout, x, A2, B2);
}